// Round 10
// baseline (1351.584 us; speedup 1.0000x reference)
//
#include <hip/hip_runtime.h>
#include <math.h>

// S=16, B=128, FEAT=2048, HAND=63, H=1024, C=1000
// out depends only on t=S-1 => 2 unroll steps from (hs[15], cs[15]).
// gates(t) = x_t @ wih^T + (bih+bhh) + h @ whh^T
// Precision: double-f16 operands (hi+lo); GEMMs accumulate 3 segments
// (Ahi*Whi + Alo*Whi + Ahi*Wlo) in f32. Recurrence drops the h-lo segment
// (h in [-1,1]) but keeps W hi+lo.
// v6.1: x-path gate GEMM (xgates + ugate) folded INTO the persistent kernel
// (block-local LDS ping-pong, computed in barrier slack). FIX vs v6: the
// unroll gate uses x[t=15] (x_h2 has rows t=0..15; t=16 was OOB).
// Cross-block h via sc1 relaxed atomics to fresh buffers (rounds 6-8 model).

typedef __attribute__((ext_vector_type(8))) _Float16 f16x8;
typedef __attribute__((ext_vector_type(4))) _Float16 f16x4;
typedef __attribute__((ext_vector_type(4))) float     f32x4;

typedef __attribute__((address_space(1))) const void as1c_void;
typedef __attribute__((address_space(3))) void       as3_void;
#define GLOAD_LDS16(g, l) \
    __builtin_amdgcn_global_load_lds((as1c_void*)(g), (as3_void*)(l), 16, 0, 0)

#define NBLK 256   // persistent blocks: 1 per CU

// ---------------------------------------------------------------------------
// MFMA GEMM, 3-segment double-f16 (xproj / classifier).
// A: [M][lda] split rows (lo at +aLoOff). W: [N][ldw] split (lo at +wLoOff).
// BM=128, BK=64, 4 waves. LDS XOR-swizzle via pre-swizzled source address.
// OUTMODE: 0 = f32 row-major; 1 = f16 split (hi at col, lo at col+ldc/2).
// ---------------------------------------------------------------------------
template<int BN, int OUTMODE, bool BIAS>
__global__ __launch_bounds__(256)
void gemm_mfma(const _Float16* __restrict__ A, int lda, int aLoOff,
               const _Float16* __restrict__ W, int ldw, int wLoOff,
               const float* __restrict__ bias,
               void* __restrict__ Cout, int ldc, int Nout,
               int ksize, long cOffPerZ)
{
    constexpr int BM = 128, BK = 64;
    constexpr int WTN = BN / 2;
    constexpr int NF  = WTN / 16;

    __shared__ _Float16 As[BM * BK];
    __shared__ _Float16 Ws[BN * BK];

    const int tid  = threadIdx.x;
    const int wave = tid >> 6, lane = tid & 63;
    const int wr = wave >> 1, wc = wave & 1;
    const int bn = blockIdx.x * BN;
    const int bm = blockIdx.y * BM;
    const long kbase = (long)blockIdx.z * ksize;

    f32x4 acc[4][NF];
    #pragma unroll
    for (int i = 0; i < 4; ++i)
        #pragma unroll
        for (int j = 0; j < NF; ++j) acc[i][j] = (f32x4){0.f, 0.f, 0.f, 0.f};

    const int srow  = tid >> 3;
    const int sbyte = (tid & 7) * 16;
    const int swzS  = (srow & 7) << 4;

    const int arow0 = wr * 64 + (lane & 15);
    const int abyte = (lane >> 4) * 16;

    for (int seg = 0; seg < 3; ++seg) {
        const int aOff = (seg == 1) ? aLoOff : 0;
        const int wOff = (seg == 2) ? wLoOff : 0;

        for (int k0 = 0; k0 < ksize; k0 += BK) {
            const long kg = kbase + k0;
            #pragma unroll
            for (int r = 0; r < 4; ++r) {
                const _Float16* src = A + ((long)(bm + 32*r + srow) * lda
                                           + aOff + kg) + ((sbyte ^ swzS) >> 1);
                GLOAD_LDS16(src, (char*)As + r*4096 + wave*1024);
            }
            #pragma unroll
            for (int r = 0; r < BN/32; ++r) {
                const _Float16* src = W + ((long)(bn + 32*r + srow) * ldw
                                           + wOff + kg) + ((sbyte ^ swzS) >> 1);
                GLOAD_LDS16(src, (char*)Ws + r*4096 + wave*1024);
            }
            __syncthreads();
            #pragma unroll
            for (int kk = 0; kk < 2; ++kk) {
                f16x8 af[4], bfr[NF];
                #pragma unroll
                for (int mi = 0; mi < 4; ++mi) {
                    const int row = arow0 + mi*16;
                    const int byi = (kk*64 + abyte) ^ ((row & 7) << 4);
                    af[mi] = *(const f16x8*)((const char*)As + row*128 + byi);
                }
                #pragma unroll
                for (int ni = 0; ni < NF; ++ni) {
                    const int row = wc*WTN + ni*16 + (lane & 15);
                    const int byi = (kk*64 + abyte) ^ ((row & 7) << 4);
                    bfr[ni] = *(const f16x8*)((const char*)Ws + row*128 + byi);
                }
                #pragma unroll
                for (int mi = 0; mi < 4; ++mi)
                    #pragma unroll
                    for (int ni = 0; ni < NF; ++ni)
                        acc[mi][ni] = __builtin_amdgcn_mfma_f32_16x16x32_f16(
                            af[mi], bfr[ni], acc[mi][ni], 0, 0, 0);
            }
            __syncthreads();
        }
    }

    float*     Cf = (float*)Cout + blockIdx.z * cOffPerZ;
    _Float16*  Ch = (_Float16*)Cout;
    #pragma unroll
    for (int mi = 0; mi < 4; ++mi) {
        #pragma unroll
        for (int ni = 0; ni < NF; ++ni) {
            const int col = bn + wc*WTN + ni*16 + (lane & 15);
            if (col < Nout) {
                const float bv = BIAS ? bias[col] : 0.f;
                #pragma unroll
                for (int r = 0; r < 4; ++r) {
                    const int row = bm + wr*64 + mi*16 + (lane >> 4)*4 + r;
                    const float v = acc[mi][ni][r] + bv;
                    if constexpr (OUTMODE == 1) {
                        _Float16 hi = (_Float16)v;
                        Ch[(long)row * ldc + col]         = hi;
                        Ch[(long)row * ldc + ldc/2 + col] = (_Float16)(v - (float)hi);
                    } else {
                        Cf[(long)row * ldc + col] = v;
                    }
                }
            }
        }
    }
}

// ---------------------------------------------------------------------------
// Persistent fused LSTM v6.1: 16 roll + 2 unroll steps + x-path gates, one
// dispatch. 256 blocks x 512 threads. Block owns 4 h-cols (16 gate cols).
// whh slice [hi|lo] LDS-resident (64.25KB, padded rows). Per step:
//   poll h(p-1) -> rec GEMM (h direct-to-reg, K=1024, W hi+lo)
//   -> Gl -> cell(xgL + Gl) -> h(p) to fresh buffer (sc1 u64) -> flag
//   -> [slack] xg slice for step p+1: x(hi|lo) @ wih(f32, inline split)
//      + bias -> block-local LDS ping-pong (no cross-block traffic).
// Unroll gate (steps 16,17) = x[15] @ un_wih^T + unb, computed in p=15 slack.
// ---------------------------------------------------------------------------
__global__ __launch_bounds__(512)
void lstm_persistent(const _Float16* __restrict__ whh,
                     const _Float16* __restrict__ uwhh,
                     const _Float16* __restrict__ x_h2,   // [2048][4096] hi|lo
                     const float* __restrict__ wih,       // [4096][2048] f32
                     const float* __restrict__ uwih,      // [4096][2048] f32
                     const float* __restrict__ rollb,     // bih+bhh [4096]
                     const float* __restrict__ unb,       // un_bih+un_bhh
                     _Float16* __restrict__ hbufs,        // 17 x 131072 (hi)
                     _Float16* __restrict__ hfin,         // [128][2048] hi|lo
                     unsigned* __restrict__ bar)
{
    constexpr int WROW = 4112;                    // 4096B data + 16B pad
    __shared__ alignas(16) char Wl[16 * WROW];    // 64.25 KB
    __shared__ float Gl[2048];                    // 8 KB   h-gates
    __shared__ float xgL[2][2048];                // 16 KB  x-gates ping-pong

    const int tid  = threadIdx.x;
    const int wave = tid >> 6, lane = tid & 63;
    const int bid  = (int)blockIdx.x;
    const int j0   = bid * 4;                     // owned h-cols

    auto stageW = [&](const _Float16* __restrict__ src) {
        const int seg = wave & 3;                 // 1KB segment of a row
        #pragma unroll
        for (int it = 0; it < 8; ++it) {
            const int g = it * 2 + (wave >> 2);   // gate-col slot 0..15
            const long G = (long)(g >> 2) * 1024 + j0 + (g & 3);
            const _Float16* s = src + G * 2048 + seg * 512 + lane * 8;
            GLOAD_LDS16(s, Wl + g * WROW + seg * 1024);
        }
    };

    // flat barrier poll: wave 0 checks all 256 flags (2 u64 loads/lane)
    auto poll = [&](unsigned ph) {
        if (wave == 0) {
            const unsigned long long* f64 = (const unsigned long long*)bar;
            for (;;) {
                unsigned long long a = __hip_atomic_load(f64 + lane,
                    __ATOMIC_RELAXED, __HIP_MEMORY_SCOPE_AGENT);
                unsigned long long b = __hip_atomic_load(f64 + 64 + lane,
                    __ATOMIC_RELAXED, __HIP_MEMORY_SCOPE_AGENT);
                const int ok = ((unsigned)a >= ph) && ((unsigned)(a >> 32) >= ph)
                            && ((unsigned)b >= ph) && ((unsigned)(b >> 32) >= ph);
                if (__all(ok)) break;
                __builtin_amdgcn_s_sleep(1);
            }
        }
        __syncthreads();
    };

    // ---- per-lane geometry ----
    const int arow = wave * 16 + (lane & 15);     // MFMA A row = batch row
    const int koff = (lane >> 4) * 8;             // k sub-slice within chunk
    const int s_   = lane & 15;                   // MFMA B col / C col
    const int G_   = (s_ >> 2) * 1024 + j0 + (s_ & 3);   // gate row for col s_
    const float biasR = rollb[G_];
    const float biasU = unb[G_];

    const int b_c = tid >> 2;                     // cell: batch row 0..127
    const int jj  = tid & 3;                      // cell: col within owned 4
    float c_reg = 0.f;

    // x-path gate slice: xg(t)[own 16 cols] -> dst (LDS), 3-seg w/ inline W split
    auto xg_gemm = [&](int t, const float* __restrict__ Wsrc, float bias,
                       float* __restrict__ dst) {
        const _Float16* xr = x_h2 + ((long)(t * 128 + arow)) * 4096 + koff;
        const float*    Wp = Wsrc + (long)G_ * 2048 + koff;
        f32x4 acc = (f32x4){bias, bias, bias, bias};
        #pragma unroll 4
        for (int i = 0; i < 64; ++i) {
            const f16x8 ahi = *(const f16x8*)(xr + i * 32);
            const f16x8 alo = *(const f16x8*)(xr + 2048 + i * 32);
            const float4 w0 = *(const float4*)(Wp + i * 32);
            const float4 w1 = *(const float4*)(Wp + i * 32 + 4);
            const float ww[8] = {w0.x, w0.y, w0.z, w0.w, w1.x, w1.y, w1.z, w1.w};
            f16x8 whi, wlo;
            #pragma unroll
            for (int e = 0; e < 8; ++e) {
                const _Float16 h = (_Float16)ww[e];
                whi[e] = h;
                wlo[e] = (_Float16)(ww[e] - (float)h);
            }
            acc = __builtin_amdgcn_mfma_f32_16x16x32_f16(ahi, whi, acc, 0, 0, 0);
            acc = __builtin_amdgcn_mfma_f32_16x16x32_f16(alo, whi, acc, 0, 0, 0);
            acc = __builtin_amdgcn_mfma_f32_16x16x32_f16(ahi, wlo, acc, 0, 0, 0);
        }
        #pragma unroll
        for (int r = 0; r < 4; ++r)
            dst[(wave * 16 + (lane >> 4) * 4 + r) * 16 + s_] = acc[r];
    };

    auto do_cell = [&](const float* __restrict__ xgbuf, bool addGl,
                       _Float16* hout, bool fin) {
        float g4[4];
        #pragma unroll
        for (int q = 0; q < 4; ++q) {
            g4[q] = xgbuf[b_c * 16 + q * 4 + jj];
            if (addGl) g4[q] += Gl[b_c * 16 + q * 4 + jj];
        }
        const float si = 1.f / (1.f + __expf(-g4[0]));
        const float sf = 1.f / (1.f + __expf(-g4[1]));
        const float so = 1.f / (1.f + __expf(-g4[3]));
        float e = __expf(-2.f * fabsf(g4[2]));
        float tg = (1.f - e) / (1.f + e); tg = g4[2] < 0.f ? -tg : tg;
        c_reg = sf * c_reg + si * tg;
        e = __expf(-2.f * fabsf(c_reg));
        float tc = (1.f - e) / (1.f + e); tc = c_reg < 0.f ? -tc : tc;
        const float hv = so * tc;
        union { _Float16 f; unsigned short u; } cv; cv.f = (_Float16)hv;
        if (fin) {                       // final step: plain stores, hi + lo
            hout[(long)b_c * 2048 + j0 + jj]        = cv.f;
            hout[(long)b_c * 2048 + 1024 + j0 + jj] = (_Float16)(hv - (float)cv.f);
        } else {                         // pack 4 cols -> one 8B sc1 store
            int w  = cv.u;
            int p2 = w | (__shfl_xor(w, 1) << 16);
            int q2 = __shfl_xor(p2, 2);
            if (jj == 0) {
                unsigned long long v = (unsigned)p2
                                     | ((unsigned long long)(unsigned)q2 << 32);
                __hip_atomic_store((unsigned long long*)(hout + (long)b_c*1024 + j0),
                                   v, __ATOMIC_RELAXED, __HIP_MEMORY_SCOPE_AGENT);
            }
        }
    };

    // ---- entry: resident weights + xg[0] ----
    stageW(whh);
    xg_gemm(0, wih, biasR, xgL[0]);
    asm volatile("s_waitcnt vmcnt(0)" ::: "memory");   // stageW landed
    __syncthreads();                                    // xgL[0] visible

    // ---- step 0: h == 0 -> gates = xg[0] -> hbufs[0], flag = 1 ----
    do_cell(xgL[0], false, hbufs, false);
    asm volatile("s_waitcnt vmcnt(0)" ::: "memory");
    __syncthreads();
    if (tid == 0)
        __hip_atomic_store(bar + bid, 1u, __ATOMIC_RELAXED,
                           __HIP_MEMORY_SCOPE_AGENT);
    xg_gemm(1, wih, biasR, xgL[1]);    // slack work for step 1

    const char* wrow = Wl + (lane & 15) * WROW + (lane >> 4) * 16;

    for (int p = 1; p < 18; ++p) {
        if (p == 16) {                   // swap in unroll weights
            stageW(uwhh);                // own Wl reads for step 15 are done
            asm volatile("s_waitcnt vmcnt(0)" ::: "memory");
        }
        poll((unsigned)p);               // h(p-1) complete everywhere

        // ---- rec GEMM: 16 rows x 16 gate-cols, K=1024 (h hi), W hi+lo ----
        const _Float16* hp = hbufs + (long)(p - 1) * 131072
                           + (long)arow * 1024 + koff;
        f16x8 af[32];
        #pragma unroll
        for (int i = 0; i < 32; ++i)
            af[i] = *(const f16x8*)(hp + (long)i * 32);

        f32x4 acch = (f32x4){0.f,0.f,0.f,0.f};
        f32x4 accl = (f32x4){0.f,0.f,0.f,0.f};
        #pragma unroll
        for (int i = 0; i < 32; ++i) {
            const f16x8 bhi = *(const f16x8*)(wrow + i * 64);
            const f16x8 blo = *(const f16x8*)(wrow + 2048 + i * 64);
            acch = __builtin_amdgcn_mfma_f32_16x16x32_f16(af[i], bhi, acch, 0, 0, 0);
            accl = __builtin_amdgcn_mfma_f32_16x16x32_f16(af[i], blo, accl, 0, 0, 0);
        }
        // Gl free: prev cell reads finished before this step's poll barrier
        #pragma unroll
        for (int r = 0; r < 4; ++r)
            Gl[(wave * 16 + (lane >> 4) * 4 + r) * 16 + (lane & 15)]
                = acch[r] + accl[r];
        __syncthreads();

        const float* xgb = (p >= 16) ? xgL[0] : xgL[p & 1];
        do_cell(xgb, true, (p == 17) ? hfin : hbufs + (long)p * 131072, p == 17);
        if (p < 17) {
            asm volatile("s_waitcnt vmcnt(0)" ::: "memory");   // h stores out
            __syncthreads();
            if (tid == 0)
                __hip_atomic_store(bar + bid, (unsigned)(p + 1),
                                   __ATOMIC_RELAXED, __HIP_MEMORY_SCOPE_AGENT);
            // slack: x-path gates for the NEXT step (own cols, own LDS)
            if (p < 15)       xg_gemm(p + 1, wih,  biasR, xgL[(p + 1) & 1]);
            else if (p == 15) xg_gemm(15,    uwih, biasU, xgL[0]);  // ugate: x[15]!
            // p == 16: step 17 reuses ugate in xgL[0]
        }
    }
}

// ---------------------------------------------------------------------------
// f32 -> split-f16 convert: rows of K become [hi(K)|lo(K)]. sh = log2(K/4).
// ---------------------------------------------------------------------------
__global__ __launch_bounds__(256)
void convert_split_g(const float* __restrict__ src, _Float16* __restrict__ dst,
                     int sh, long n4)
{
    const long i = (long)blockIdx.x * 256 + threadIdx.x;
    if (i >= n4) return;
    const long row = i >> sh;
    const long k4  = i & ((1L << sh) - 1);
    const float4 v = ((const float4*)src)[i];
    const float vv[4] = {v.x, v.y, v.z, v.w};
    f16x4 hi, lo;
    #pragma unroll
    for (int j = 0; j < 4; ++j) {
        hi[j] = (_Float16)vv[j];
        lo[j] = (_Float16)(vv[j] - (float)hi[j]);
    }
    ((f16x4*)dst)[(row << (sh + 1)) + k4]              = hi;
    ((f16x4*)dst)[(row << (sh + 1)) + (1L << sh) + k4] = lo;
}

__global__ __launch_bounds__(256)
void bias_sum(const float* __restrict__ a1, const float* __restrict__ b1,
              const float* __restrict__ a2, const float* __restrict__ b2,
              float* __restrict__ o1, float* __restrict__ o2)
{
    const int i = blockIdx.x * 256 + threadIdx.x;
    if (i < 4096) { o1[i] = a1[i] + b1[i]; o2[i] = a2[i] + b2[i]; }
}

// ---------------------------------------------------------------------------
// hproj: x[:, 1024:2048] = concat(lh,rh) @ fch_w^T + fch_b (K=126), split out.
// ---------------------------------------------------------------------------
__global__ __launch_bounds__(256)
void hproj_kernel(const float* __restrict__ lh, const float* __restrict__ rh,
                  const float* __restrict__ fchw, const float* __restrict__ fchb,
                  _Float16* __restrict__ x)
{
    __shared__ float hs[16][126];
    const int brow = blockIdx.x * 16;
    for (int idx = threadIdx.x; idx < 16 * 126; idx += 256) {
        const int r = idx / 126, k = idx % 126;
        const int grow = brow + r;
        hs[r][k] = (k < 63) ? lh[(long)grow * 63 + k]
                            : rh[(long)grow * 63 + (k - 63)];
    }
    __syncthreads();
    for (int j = threadIdx.x; j < 1024; j += 256) {
        float acc[16];
        #pragma unroll
        for (int r = 0; r < 16; ++r) acc[r] = 0.f;
        const float* wrow = fchw + (long)j * 126;
        for (int k = 0; k < 126; ++k) {
            const float w = wrow[k];
            #pragma unroll
            for (int r = 0; r < 16; ++r) acc[r] = fmaf(w, hs[r][k], acc[r]);
        }
        const float b = fchb[j];
        #pragma unroll
        for (int r = 0; r < 16; ++r) {
            const float v = acc[r] + b;
            const _Float16 hi = (_Float16)v;
            x[(long)(brow + r) * 4096 + 1024 + j] = hi;
            x[(long)(brow + r) * 4096 + 3072 + j] = (_Float16)(v - (float)hi);
        }
    }
}

// ---------------------------------------------------------------------------
// Head: per-row argmax (first-max tie-break) + logsumexp + per-row loss.
// ---------------------------------------------------------------------------
__global__ __launch_bounds__(256)
void head_kernel(const float* __restrict__ logits, const int* __restrict__ act,
                 float* __restrict__ d_out, float* __restrict__ lossbuf)
{
    const int b = blockIdx.x;
    const int tid = threadIdx.x;
    const float* row = logits + (long)b * 1000;

    float mx = -1e30f; int mi = 1 << 30;
    for (int j = tid; j < 1000; j += 256) {
        const float v = row[j];
        if (v > mx) { mx = v; mi = j; }
    }
    __shared__ float smx[256];
    __shared__ int   smi[256];
    smx[tid] = mx; smi[tid] = mi;
    __syncthreads();
    for (int s = 128; s > 0; s >>= 1) {
        if (tid < s) {
            const float v2 = smx[tid + s]; const int i2 = smi[tid + s];
            if (v2 > smx[tid] || (v2 == smx[tid] && i2 < smi[tid])) {
                smx[tid] = v2; smi[tid] = i2;
            }
        }
        __syncthreads();
    }
    const float gmx = smx[0];
    const int   gmi = smi[0];
    __syncthreads();

    float partial = 0.f;
    for (int j = tid; j < 1000; j += 256) partial += __expf(row[j] - gmx);
    smx[tid] = partial;
    __syncthreads();
    for (int s = 128; s > 0; s >>= 1) {
        if (tid < s) smx[tid] += smx[tid + s];
        __syncthreads();
    }
    if (tid == 0) {
        d_out[128000 + b] = (float)gmi;
        lossbuf[b] = gmx + logf(smx[0]) - row[act[b]];
    }
}

__global__ __launch_bounds__(128)
void loss_reduce(const float* __restrict__ lossbuf, float* __restrict__ d_out)
{
    __shared__ float s[128];
    const int tid = threadIdx.x;
    s[tid] = lossbuf[tid];
    __syncthreads();
    for (int k = 64; k > 0; k >>= 1) {
        if (tid < k) s[tid] += s[tid + k];
        __syncthreads();
    }
    if (tid == 0) d_out[128128] = s[0] / 128.f;
}

// ---------------------------------------------------------------------------
extern "C" void kernel_launch(void* const* d_in, const int* in_sizes, int n_in,
                              void* d_out, int out_size, void* d_ws, size_t ws_size,
                              hipStream_t stream)
{
    const float* feats    = (const float*)d_in[0];
    const float* lh       = (const float*)d_in[1];
    const float* rh       = (const float*)d_in[2];
    const int*   act      = (const int*)  d_in[3];
    const float* fc1_w    = (const float*)d_in[4];
    const float* fc1_b    = (const float*)d_in[5];
    const float* fch_w    = (const float*)d_in[6];
    const float* fch_b    = (const float*)d_in[7];
    const float* roll_wih = (const float*)d_in[8];
    const float* roll_whh = (const float*)d_in[9];
    const float* roll_bih = (const float*)d_in[10];
    const float* roll_bhh = (const float*)d_in[11];
    const float* un_wih   = (const float*)d_in[12];
    const float* un_whh   = (const float*)d_in[13];
    const float* un_bih   = (const float*)d_in[14];
    const float* un_bhh   = (const float*)d_in[15];
    const float* cls_w    = (const float*)d_in[16];
    const float* cls_b    = (const float*)d_in[17];

    float* out = (float*)d_out;
    char* ws = (char*)d_ws;
    size_t o = 0;
    auto alloc = [&](size_t b) { size_t r = o; o += (b + 255) & ~(size_t)255; return r; };

    // all regions disjoint (peak ~81 MiB)
    _Float16* x_h2     = (_Float16*)(ws + alloc(2048ul*4096*2));   // 16 MiB
    _Float16* feats_h2 = (_Float16*)(ws + alloc(2048ul*4096*2));   // 16 MiB
    _Float16* whhr_h2  = (_Float16*)(ws + alloc(4096ul*2048*2));   // 16 MiB
    _Float16* unwhh_h2 = (_Float16*)(ws + alloc(4096ul*2048*2));   // 16 MiB
    _Float16* fc1w_h2  = (_Float16*)(ws + alloc(1024ul*4096*2));   //  8 MiB
    _Float16* clsw_h2  = (_Float16*)(ws + alloc(1000ul*2048*2));   //  4 MiB
    _Float16* hbufs    = (_Float16*)(ws + alloc(17ul*131072*2));   // 4.25 MiB
    _Float16* h_h2     = (_Float16*)(ws + alloc(128ul*2048*2));    // 512 KiB
    float*    rollb    = (float*)   (ws + alloc(4096*4));
    float*    unb      = (float*)   (ws + alloc(4096*4));
    float*    lossbuf  = (float*)   (ws + alloc(128*4));
    unsigned* barctr   = (unsigned*)(ws + alloc(2048));

    // ---- conversions ----
    convert_split_g<<<4096, 256, 0, stream>>>(feats,    feats_h2, 9, 1048576);
    convert_split_g<<<4096, 256, 0, stream>>>(roll_whh, whhr_h2,  8, 1048576);
    convert_split_g<<<4096, 256, 0, stream>>>(un_whh,   unwhh_h2, 8, 1048576);
    convert_split_g<<<2048, 256, 0, stream>>>(fc1_w,    fc1w_h2,  9, 524288);
    convert_split_g<<<1000, 256, 0, stream>>>(cls_w,    clsw_h2,  8, 256000);
    bias_sum<<<16, 256, 0, stream>>>(roll_bih, roll_bhh, un_bih, un_bhh, rollb, unb);
    hipMemsetAsync(barctr, 0, 2048, stream);

    // ---- x = [xproj | hproj] ----
    gemm_mfma<128, 1, true><<<dim3(8, 16, 1), 256, 0, stream>>>(
        feats_h2, 4096, 2048, fc1w_h2, 4096, 2048, fc1_b,
        x_h2, 4096, 1024, 2048, 0);
    hproj_kernel<<<128, 256, 0, stream>>>(lh, rh, fch_w, fch_b, x_h2);

    // ---- fused recurrence + x-path gates: one dispatch ----
    lstm_persistent<<<NBLK, 512, 0, stream>>>(
        whhr_h2, unwhh_h2, x_h2, roll_wih, un_wih, rollb, unb,
        hbufs, h_h2, barctr);

    // ---- classifier + head ----
    gemm_mfma<64, 0, true><<<dim3(16, 1, 1), 256, 0, stream>>>(
        h_h2, 2048, 1024, clsw_h2, 2048, 1024, cls_b, out, 1000, 1000, 1024, 0);
    head_kernel<<<128, 256, 0, stream>>>(out, act, out, lossbuf);
    loss_reduce<<<1, 128, 0, stream>>>(lossbuf, out);
}

// Round 11
// 592.618 us; speedup vs baseline: 2.2807x; 2.2807x over previous
//
#include <hip/hip_runtime.h>
#include <math.h>

// S=16, B=128, FEAT=2048, HAND=63, H=1024, C=1000
// out depends only on t=S-1 => 2 unroll steps from (hs[15], cs[15]).
// gates(t) = [x_t @ wih^T + bih + bhh] (hoisted) + h @ whh^T
// Precision: double-f16 operands (hi+lo); GEMMs accumulate 3 segments
// (Ahi*Whi + Alo*Whi + Ahi*Wlo) in f32. Recurrence drops the h-lo segment
// (h in [-1,1]) but keeps W hi+lo.
// Recurrence coherence model (validated rounds 6-8): h(t) -> FRESH buffer per
// step via sc1 relaxed atomic stores (land at LLC); readers use coalesced
// global_load_lds (fresh addresses never stale within a dispatch;
// dispatch-boundary invalidation covers graph replays). Flags via sc1.

typedef __attribute__((ext_vector_type(8))) _Float16 f16x8;
typedef __attribute__((ext_vector_type(4))) _Float16 f16x4;
typedef __attribute__((ext_vector_type(4))) float     f32x4;

typedef __attribute__((address_space(1))) const void as1c_void;
typedef __attribute__((address_space(3))) void       as3_void;
#define GLOAD_LDS16(g, l) \
    __builtin_amdgcn_global_load_lds((as1c_void*)(g), (as3_void*)(l), 16, 0, 0)

#define NBLK 256   // persistent blocks: 1 per CU (128KB LDS forces it)

// ---------------------------------------------------------------------------
// MFMA GEMM, 3-segment double-f16. A: [M][lda] split rows (lo at +aLoOff).
// W: [N][ldw] split rows (lo at +wLoOff). BM=128, BK=64, 4 waves (2x2).
// LDS XOR-swizzle byte^=((row&7)<<4) via pre-swizzled source address.
// grid.z = K-split slice of ksize; partial out at Cf + z*cOffPerZ.
// OUTMODE: 0 = f32 row-major; 1 = f16 split (hi at col, lo at col+ldc/2);
//          2 = f32 xg-transposed [t][jgroup][b][jj][q] (t=row>>7,b=row&127).
// ---------------------------------------------------------------------------
template<int BN, int OUTMODE, bool BIAS>
__global__ __launch_bounds__(256)
void gemm_mfma(const _Float16* __restrict__ A, int lda, int aLoOff,
               const _Float16* __restrict__ W, int ldw, int wLoOff,
               const float* __restrict__ bias,
               void* __restrict__ Cout, int ldc, int Nout,
               int ksize, long cOffPerZ)
{
    constexpr int BM = 128, BK = 64;
    constexpr int WTN = BN / 2;
    constexpr int NF  = WTN / 16;

    __shared__ _Float16 As[BM * BK];
    __shared__ _Float16 Ws[BN * BK];

    const int tid  = threadIdx.x;
    const int wave = tid >> 6, lane = tid & 63;
    const int wr = wave >> 1, wc = wave & 1;
    const int bn = blockIdx.x * BN;
    const int bm = blockIdx.y * BM;
    const long kbase = (long)blockIdx.z * ksize;

    f32x4 acc[4][NF];
    #pragma unroll
    for (int i = 0; i < 4; ++i)
        #pragma unroll
        for (int j = 0; j < NF; ++j) acc[i][j] = (f32x4){0.f, 0.f, 0.f, 0.f};

    const int srow  = tid >> 3;          // 0..31
    const int sbyte = (tid & 7) * 16;
    const int swzS  = (srow & 7) << 4;

    const int arow0 = wr * 64 + (lane & 15);
    const int abyte = (lane >> 4) * 16;

    for (int seg = 0; seg < 3; ++seg) {
        const int aOff = (seg == 1) ? aLoOff : 0;
        const int wOff = (seg == 2) ? wLoOff : 0;

        for (int k0 = 0; k0 < ksize; k0 += BK) {
            const long kg = kbase + k0;
            #pragma unroll
            for (int r = 0; r < 4; ++r) {
                const _Float16* src = A + ((long)(bm + 32*r + srow) * lda
                                           + aOff + kg) + ((sbyte ^ swzS) >> 1);
                GLOAD_LDS16(src, (char*)As + r*4096 + wave*1024);
            }
            #pragma unroll
            for (int r = 0; r < BN/32; ++r) {
                const _Float16* src = W + ((long)(bn + 32*r + srow) * ldw
                                           + wOff + kg) + ((sbyte ^ swzS) >> 1);
                GLOAD_LDS16(src, (char*)Ws + r*4096 + wave*1024);
            }
            __syncthreads();
            #pragma unroll
            for (int kk = 0; kk < 2; ++kk) {
                f16x8 af[4], bfr[NF];
                #pragma unroll
                for (int mi = 0; mi < 4; ++mi) {
                    const int row = arow0 + mi*16;
                    const int byi = (kk*64 + abyte) ^ ((row & 7) << 4);
                    af[mi] = *(const f16x8*)((const char*)As + row*128 + byi);
                }
                #pragma unroll
                for (int ni = 0; ni < NF; ++ni) {
                    const int row = wc*WTN + ni*16 + (lane & 15);
                    const int byi = (kk*64 + abyte) ^ ((row & 7) << 4);
                    bfr[ni] = *(const f16x8*)((const char*)Ws + row*128 + byi);
                }
                #pragma unroll
                for (int mi = 0; mi < 4; ++mi)
                    #pragma unroll
                    for (int ni = 0; ni < NF; ++ni)
                        acc[mi][ni] = __builtin_amdgcn_mfma_f32_16x16x32_f16(
                            af[mi], bfr[ni], acc[mi][ni], 0, 0, 0);
            }
            __syncthreads();
        }
    }

    float*     Cf = (float*)Cout + blockIdx.z * cOffPerZ;
    _Float16*  Ch = (_Float16*)Cout;
    #pragma unroll
    for (int mi = 0; mi < 4; ++mi) {
        #pragma unroll
        for (int ni = 0; ni < NF; ++ni) {
            const int col = bn + wc*WTN + ni*16 + (lane & 15);
            if (col < Nout) {
                const float bv = BIAS ? bias[col] : 0.f;
                #pragma unroll
                for (int r = 0; r < 4; ++r) {
                    const int row = bm + wr*64 + mi*16 + (lane >> 4)*4 + r;
                    const float v = acc[mi][ni][r] + bv;
                    if constexpr (OUTMODE == 1) {
                        _Float16 hi = (_Float16)v;
                        Ch[(long)row * ldc + col]         = hi;
                        Ch[(long)row * ldc + ldc/2 + col] = (_Float16)(v - (float)hi);
                    } else if constexpr (OUTMODE == 2) {
                        const int t = row >> 7, b = row & 127;
                        const int q = col >> 10, j = col & 1023;
                        Cf[(long)t*524288 + (long)(j>>2)*2048
                           + b*16 + (j&3)*4 + q] = v;
                    } else {
                        Cf[(long)row * ldc + col] = v;
                    }
                }
            }
        }
    }
}

// ---------------------------------------------------------------------------
// Persistent fused LSTM v4 (round-7 proven): 16 roll + 2 unroll steps, one
// dispatch. 256 blocks x 512 threads, 1 block/CU (128KB LDS). Block owns 4
// h-cols (16 gate cols); whh slice [hi|lo] LDS-resident (64KB). Per step:
// h(t-1) (256KB, hi only) staged via coalesced global_load_lds in 8 chunks
// of K=128, double-buffered, counted vmcnt. h(t) to a fresh buffer via
// packed sc1 u64 stores. Flat wave-parallel flag barrier.
// ---------------------------------------------------------------------------
__global__ __launch_bounds__(512)
void lstm_persistent(const _Float16* __restrict__ whh,
                     const _Float16* __restrict__ uwhh,
                     const float* __restrict__ xgT,
                     const float* __restrict__ ugT,
                     _Float16* __restrict__ hbufs,   // 17 x 131072 (hi only)
                     _Float16* __restrict__ hfin,    // [128][2048] hi|lo
                     unsigned* __restrict__ bar)
{
    __shared__ alignas(16) _Float16 Wl[16 * 2048];     // 64KB
    __shared__ alignas(16) _Float16 As[2][128 * 128];  // 2 x 32KB
    float* Gl = (float*)&As[0][0];                     // 8KB overlay (post-mma)

    const int tid  = threadIdx.x;
    const int wave = tid >> 6, lane = tid & 63;
    const int bid  = (int)blockIdx.x;
    const int j0   = bid * 4;            // owned h-cols

    // flat barrier: store own flag; wave 0 polls all 256 flags in parallel
    auto grid_barrier = [&](unsigned ph) {
        __syncthreads();                 // drains all waves' vmcnt (h stores)
        if (wave == 0) {
            if (lane == 0)
                __hip_atomic_store(bar + bid, ph, __ATOMIC_RELAXED,
                                   __HIP_MEMORY_SCOPE_AGENT);
            const unsigned long long* b64 = (const unsigned long long*)bar;
            for (;;) {
                unsigned long long a = __hip_atomic_load(b64 + lane,
                    __ATOMIC_RELAXED, __HIP_MEMORY_SCOPE_AGENT);
                unsigned long long c = __hip_atomic_load(b64 + 64 + lane,
                    __ATOMIC_RELAXED, __HIP_MEMORY_SCOPE_AGENT);
                const int ok = ((unsigned)a >= ph) && ((unsigned)(a >> 32) >= ph)
                            && ((unsigned)c >= ph) && ((unsigned)(c >> 32) >= ph);
                if (__all(ok)) break;
                __builtin_amdgcn_s_sleep(1);
            }
        }
        __syncthreads();
    };

    auto stageW = [&](const _Float16* __restrict__ src) {
        const int byte = (tid & 255) * 16;
        #pragma unroll
        for (int it = 0; it < 8; ++it) {
            const int g = it * 2 + (wave >> 2);
            const long G = (long)(g >> 2) * 1024 + j0 + (g & 3);
            const _Float16* s = src + G * 2048 + ((byte ^ ((g & 7) << 4)) >> 1);
            GLOAD_LDS16(s, (char*)Wl + g * 4096 + (wave & 3) * 1024);
        }
    };

    const int b_c = tid >> 2;            // cell: batch row 0..127
    const int jj  = tid & 3;             // cell: col within owned 4
    float c_reg = 0.f;

    auto do_cell = [&](float4 xgv, bool addGl, _Float16* hout, bool fin) {
        float g4[4] = {xgv.x, xgv.y, xgv.z, xgv.w};
        if (addGl) {
            #pragma unroll
            for (int q = 0; q < 4; ++q) g4[q] += Gl[b_c * 16 + q * 4 + jj];
        }
        const float si = 1.f / (1.f + __expf(-g4[0]));
        const float sf = 1.f / (1.f + __expf(-g4[1]));
        const float so = 1.f / (1.f + __expf(-g4[3]));
        float e = __expf(-2.f * fabsf(g4[2]));
        float tg = (1.f - e) / (1.f + e); tg = g4[2] < 0.f ? -tg : tg;
        c_reg = sf * c_reg + si * tg;
        e = __expf(-2.f * fabsf(c_reg));
        float tc = (1.f - e) / (1.f + e); tc = c_reg < 0.f ? -tc : tc;
        const float hv = so * tc;
        union { _Float16 f; unsigned short u; } cv; cv.f = (_Float16)hv;
        if (fin) {                       // final step: plain stores, hi + lo
            hout[(long)b_c * 2048 + j0 + jj]        = cv.f;
            hout[(long)b_c * 2048 + 1024 + j0 + jj] = (_Float16)(hv - (float)cv.f);
        } else {                         // pack 4 cols -> one 8B sc1 store
            int w  = cv.u;
            int p2 = w | (__shfl_xor(w, 1) << 16);
            int q2 = __shfl_xor(p2, 2);
            if (jj == 0) {
                unsigned long long v = (unsigned)p2
                                     | ((unsigned long long)(unsigned)q2 << 32);
                __hip_atomic_store((unsigned long long*)(hout + (long)b_c*1024 + j0),
                                   v, __ATOMIC_RELAXED, __HIP_MEMORY_SCOPE_AGENT);
            }
        }
    };

    stageW(whh);   // drained by grid_barrier(1)'s syncthreads

    // ---- step 0: h == 0 -> gates = xg[0] ----
    const long xoff = (long)bid * 2048 + b_c * 16 + jj * 4;
    { float4 x0 = *(const float4*)(xgT + xoff); do_cell(x0, false, hbufs, false); }
    grid_barrier(1);

    // staging geometry: thread covers (row = pass*32 + wave*4 + (lane>>4)),
    // 16B at byte (lane&15)*16 of the 256B chunk-row; LDS dest linear.
    const int srow_w = wave * 4 + (lane >> 4);
    const int sb     = (lane & 15) * 16;
    // MFMA fragment geometry
    const int arow = wave * 16 + (lane & 15);          // batch row
    const int aswz = (arow & 7) << 4;
    const char* wrow = (const char*)Wl + (lane & 15) * 4096;
    const int wswz = (lane & 7) << 4;                  // ((g&7)<<4), g=lane&15

    for (int p = 1; p < 18; ++p) {
        if (p == 16) {                   // swap in unroll weights
            stageW(uwhh);
            asm volatile("s_waitcnt vmcnt(0)" ::: "memory");
            __syncthreads();
        }
        const float* xsrc = (p <= 15) ? xgT + (long)p * 524288 : ugT;
        float4 xcur = *(const float4*)(xsrc + xoff);
        const _Float16* hprev = hbufs + (long)(p - 1) * 131072;

        auto issue = [&](int ck, int buf) {
            #pragma unroll
            for (int pass = 0; pass < 4; ++pass) {
                const int row = pass * 32 + srow_w;
                const _Float16* src = hprev + (long)row * 1024 + ck * 128
                                    + ((sb ^ ((row & 7) << 4)) >> 1);
                GLOAD_LDS16(src, (char*)&As[buf][0] + pass*8192 + wave*1024);
            }
        };
        issue(0, 0);

        f32x4 acc = (f32x4){0.f, 0.f, 0.f, 0.f};
        for (int ck = 0; ck < 8; ++ck) {
            __builtin_amdgcn_s_barrier();            // prev mma done everywhere
            if (ck < 7) {
                issue(ck + 1, (ck + 1) & 1);
                asm volatile("s_waitcnt vmcnt(4)" ::: "memory");  // ck landed
            } else {
                asm volatile("s_waitcnt vmcnt(0)" ::: "memory");
            }
            __builtin_amdgcn_s_barrier();            // chunk ck visible to all
            const char* abase = (const char*)&As[ck & 1][0] + arow * 256;
            #pragma unroll
            for (int kb = 0; kb < 4; ++kb) {
                const int ab = kb * 64 + ((lane >> 4) << 4);
                const f16x8 a   = *(const f16x8*)(abase + (ab ^ aswz));
                const int  wb  = ck * 256 + ab;
                const f16x8 bhi = *(const f16x8*)(wrow + ((wb ^ wswz)));
                const f16x8 blo = *(const f16x8*)(wrow + 2048 + ((wb ^ wswz)));
                acc = __builtin_amdgcn_mfma_f32_16x16x32_f16(a, bhi, acc, 0, 0, 0);
                acc = __builtin_amdgcn_mfma_f32_16x16x32_f16(a, blo, acc, 0, 0, 0);
            }
        }
        __syncthreads();                 // all mma done -> Gl overlay safe
        #pragma unroll
        for (int r = 0; r < 4; ++r)
            Gl[(wave * 16 + (lane >> 4) * 4 + r) * 16 + (lane & 15)] = acc[r];
        __syncthreads();

        do_cell(xcur, true,
                (p == 17) ? hfin : hbufs + (long)p * 131072, p == 17);
        if (p < 17) grid_barrier(p + 1);
    }
}

// ---------------------------------------------------------------------------
// Fused multi-tensor f32 -> split-f16 convert (rows [hi(K)|lo(K)]) + bias
// sums. Up to 4 ranges (n in float4 units, sh = log2(K/4)); bias range last.
// ---------------------------------------------------------------------------
__global__ __launch_bounds__(256)
void convert_multi(const float* __restrict__ s0, _Float16* __restrict__ d0, long n0, int sh0,
                   const float* __restrict__ s1, _Float16* __restrict__ d1, long n1, int sh1,
                   const float* __restrict__ s2, _Float16* __restrict__ d2, long n2, int sh2,
                   const float* __restrict__ s3, _Float16* __restrict__ d3, long n3, int sh3,
                   const float* __restrict__ ba1, const float* __restrict__ bb1,
                   const float* __restrict__ ba2, const float* __restrict__ bb2,
                   float* __restrict__ o1, float* __restrict__ o2, long nb4)
{
    long i = (long)blockIdx.x * 256 + threadIdx.x;
    const float* s; _Float16* d; int sh;
    if (i < n0)      { s = s0; d = d0; sh = sh0; }
    else { i -= n0;
    if (i < n1)      { s = s1; d = d1; sh = sh1; }
    else { i -= n1;
    if (i < n2)      { s = s2; d = d2; sh = sh2; }
    else { i -= n2;
    if (i < n3)      { s = s3; d = d3; sh = sh3; }
    else { i -= n3;
        if (i >= nb4) return;
        const long half = nb4 >> 1;
        const bool first = (i < half);
        const long k = first ? i : (i - half);
        const float4 a = ((const float4*)(first ? ba1 : ba2))[k];
        const float4 b = ((const float4*)(first ? bb1 : bb2))[k];
        float4 r; r.x = a.x + b.x; r.y = a.y + b.y;
                  r.z = a.z + b.z; r.w = a.w + b.w;
        ((float4*)(first ? o1 : o2))[k] = r;
        return;
    }}}}
    const long row = i >> sh;
    const long k4  = i & ((1L << sh) - 1);
    const float4 v = ((const float4*)s)[i];
    const float vv[4] = {v.x, v.y, v.z, v.w};
    f16x4 hi, lo;
    #pragma unroll
    for (int j = 0; j < 4; ++j) {
        hi[j] = (_Float16)vv[j];
        lo[j] = (_Float16)(vv[j] - (float)hi[j]);
    }
    ((f16x4*)d)[(row << (sh + 1)) + k4]              = hi;
    ((f16x4*)d)[(row << (sh + 1)) + (1L << sh) + k4] = lo;
}

// ---------------------------------------------------------------------------
// hproj: x[:, 1024:2048] = concat(lh,rh) @ fch_w^T + fch_b (K=126), split out.
// ---------------------------------------------------------------------------
__global__ __launch_bounds__(256)
void hproj_kernel(const float* __restrict__ lh, const float* __restrict__ rh,
                  const float* __restrict__ fchw, const float* __restrict__ fchb,
                  _Float16* __restrict__ x)
{
    __shared__ float hs[16][126];
    const int brow = blockIdx.x * 16;
    for (int idx = threadIdx.x; idx < 16 * 126; idx += 256) {
        const int r = idx / 126, k = idx % 126;
        const int grow = brow + r;
        hs[r][k] = (k < 63) ? lh[(long)grow * 63 + k]
                            : rh[(long)grow * 63 + (k - 63)];
    }
    __syncthreads();
    for (int j = threadIdx.x; j < 1024; j += 256) {
        float acc[16];
        #pragma unroll
        for (int r = 0; r < 16; ++r) acc[r] = 0.f;
        const float* wrow = fchw + (long)j * 126;
        for (int k = 0; k < 126; ++k) {
            const float w = wrow[k];
            #pragma unroll
            for (int r = 0; r < 16; ++r) acc[r] = fmaf(w, hs[r][k], acc[r]);
        }
        const float b = fchb[j];
        #pragma unroll
        for (int r = 0; r < 16; ++r) {
            const float v = acc[r] + b;
            const _Float16 hi = (_Float16)v;
            x[(long)(brow + r) * 4096 + 1024 + j] = hi;
            x[(long)(brow + r) * 4096 + 3072 + j] = (_Float16)(v - (float)hi);
        }
    }
}

// ugate = sum of 4 K-split partials + bias, output in xg-transposed layout.
__global__ __launch_bounds__(256)
void reduce4_bias(const float* __restrict__ part, const float* __restrict__ bias,
                  float* __restrict__ out)
{
    const int t = blockIdx.x * 256 + threadIdx.x;
    const long o = (long)t * 4;
    const int b   = (int)(o >> 12);
    const int rem = (int)(o & 4095);
    const int q   = rem >> 10, jb = rem & 1023;
    float4 s = *(const float4*)(part + o);
    #pragma unroll
    for (int p = 1; p < 4; ++p) {
        const float4 v = *(const float4*)(part + (long)p*524288 + o);
        s.x += v.x; s.y += v.y; s.z += v.z; s.w += v.w;
    }
    const float4 bb = *(const float4*)(bias + rem);
    const float sv[4] = {s.x + bb.x, s.y + bb.y, s.z + bb.z, s.w + bb.w};
    #pragma unroll
    for (int e = 0; e < 4; ++e) {
        const int j = jb + e;
        out[(long)(j >> 2) * 2048 + b * 16 + (j & 3) * 4 + q] = sv[e];
    }
}

// ---------------------------------------------------------------------------
// Head: per-row argmax (first-max tie-break) + logsumexp + per-row loss.
// ---------------------------------------------------------------------------
__global__ __launch_bounds__(256)
void head_kernel(const float* __restrict__ logits, const int* __restrict__ act,
                 float* __restrict__ d_out, float* __restrict__ lossbuf)
{
    const int b = blockIdx.x;
    const int tid = threadIdx.x;
    const float* row = logits + (long)b * 1000;

    float mx = -1e30f; int mi = 1 << 30;
    for (int j = tid; j < 1000; j += 256) {
        const float v = row[j];
        if (v > mx) { mx = v; mi = j; }
    }
    __shared__ float smx[256];
    __shared__ int   smi[256];
    smx[tid] = mx; smi[tid] = mi;
    __syncthreads();
    for (int s = 128; s > 0; s >>= 1) {
        if (tid < s) {
            const float v2 = smx[tid + s]; const int i2 = smi[tid + s];
            if (v2 > smx[tid] || (v2 == smx[tid] && i2 < smi[tid])) {
                smx[tid] = v2; smi[tid] = i2;
            }
        }
        __syncthreads();
    }
    const float gmx = smx[0];
    const int   gmi = smi[0];
    __syncthreads();

    float partial = 0.f;
    for (int j = tid; j < 1000; j += 256) partial += __expf(row[j] - gmx);
    smx[tid] = partial;
    __syncthreads();
    for (int s = 128; s > 0; s >>= 1) {
        if (tid < s) smx[tid] += smx[tid + s];
        __syncthreads();
    }
    if (tid == 0) {
        d_out[128000 + b] = (float)gmi;
        lossbuf[b] = gmx + logf(smx[0]) - row[act[b]];
    }
}

__global__ __launch_bounds__(128)
void loss_reduce(const float* __restrict__ lossbuf, float* __restrict__ d_out)
{
    __shared__ float s[128];
    const int tid = threadIdx.x;
    s[tid] = lossbuf[tid];
    __syncthreads();
    for (int k = 64; k > 0; k >>= 1) {
        if (tid < k) s[tid] += s[tid + k];
        __syncthreads();
    }
    if (tid == 0) d_out[128128] = s[0] / 128.f;
}

// ---------------------------------------------------------------------------
extern "C" void kernel_launch(void* const* d_in, const int* in_sizes, int n_in,
                              void* d_out, int out_size, void* d_ws, size_t ws_size,
                              hipStream_t stream)
{
    const float* feats    = (const float*)d_in[0];
    const float* lh       = (const float*)d_in[1];
    const float* rh       = (const float*)d_in[2];
    const int*   act      = (const int*)  d_in[3];
    const float* fc1_w    = (const float*)d_in[4];
    const float* fc1_b    = (const float*)d_in[5];
    const float* fch_w    = (const float*)d_in[6];
    const float* fch_b    = (const float*)d_in[7];
    const float* roll_wih = (const float*)d_in[8];
    const float* roll_whh = (const float*)d_in[9];
    const float* roll_bih = (const float*)d_in[10];
    const float* roll_bhh = (const float*)d_in[11];
    const float* un_wih   = (const float*)d_in[12];
    const float* un_whh   = (const float*)d_in[13];
    const float* un_bih   = (const float*)d_in[14];
    const float* un_bhh   = (const float*)d_in[15];
    const float* cls_w    = (const float*)d_in[16];
    const float* cls_b    = (const float*)d_in[17];

    float* out = (float*)d_out;
    char* ws = (char*)d_ws;
    size_t o = 0;
    auto alloc = [&](size_t b) { size_t r = o; o += (b + 255) & ~(size_t)255; return r; };

    // regions (temporal aliasing documented inline)
    _Float16* x_h2     = (_Float16*)(ws + alloc(2048ul*4096*2));   // A: x split, 16MiB
    char*     regB     = ws + alloc(2048ul*4096*2);                // B: 16MiB
    char*     regC     = ws + alloc(4096ul*4096*2);                // C: 32MiB
    _Float16* whhr_h2  = (_Float16*)(ws + alloc(4096ul*2048*2));   // D: 16MiB
    char*     regE     = ws + alloc(16ul*128*4096*4);              // E: 32MiB
    float*    ugate    = (float*)   (ws + alloc(128ul*4096*4));    // F: 2MiB
    _Float16* h_h2     = (_Float16*)(ws + alloc(128ul*2048*2));    // G: 512KiB
    float*    rollb    = (float*)   (ws + alloc(4096*4));
    float*    unb      = (float*)   (ws + alloc(4096*4));
    float*    lossbuf  = (float*)   (ws + alloc(128*4));
    unsigned* barctr   = (unsigned*)(ws + alloc(2048));

    _Float16* feats_h2 = (_Float16*)regB;                 // dead after xproj
    float*    part     = (float*)regB;                    // ugate partials (8MiB)
    _Float16* clsw_h2  = (_Float16*)(regB + (8ul<<20));   // 4MiB, after part dead
    _Float16* wihr_h2  = (_Float16*)regC;                 // dead after xgates
    _Float16* unwhh_h2 = (_Float16*)regC;                 // after xgates (16MiB)
    _Float16* hbufs    = (_Float16*)(regC + (16ul<<20));  // 17x256KB, after xgates
    _Float16* fc1w_h2  = (_Float16*)regE;                 // dead after xproj
    _Float16* unwih_h2 = (_Float16*)regE;                 // after xproj, dead after ugate
    float*    xgates   = (float*)regE;                    // after ugate (transposed)

    // ---- conversions wave 1: feats, roll_wih, roll_whh, fc1_w + biases ----
    // ranges (float4): 1048576 + 2097152 + 1048576 + 524288 + 2048 = 4720640
    convert_multi<<<18440, 256, 0, stream>>>(
        feats,    feats_h2, 1048576, 9,
        roll_wih, wihr_h2,  2097152, 9,
        roll_whh, whhr_h2,  1048576, 8,
        fc1_w,    fc1w_h2,  524288,  9,
        roll_bih, roll_bhh, un_bih, un_bhh, rollb, unb, 2048);
    hipMemsetAsync(barctr, 0, 2048, stream);

    // ---- x = [xproj | hproj] ----
    gemm_mfma<64, 1, true><<<dim3(16, 16, 1), 256, 0, stream>>>(
        feats_h2, 4096, 2048, fc1w_h2, 4096, 2048, fc1_b,
        x_h2, 4096, 1024, 2048, 0);
    hproj_kernel<<<128, 256, 0, stream>>>(lh, rh, fch_w, fch_b, x_h2);

    // ---- conversions wave 2: un_wih (into E, after xproj freed fc1w) ----
    convert_multi<<<8192, 256, 0, stream>>>(
        un_wih, unwih_h2, 2097152, 9,
        nullptr, nullptr, 0, 0, nullptr, nullptr, 0, 0, nullptr, nullptr, 0, 0,
        nullptr, nullptr, nullptr, nullptr, nullptr, nullptr, 0);

    // ---- ugate = x[15] @ un_wih^T + unb (K=2048 split over 4 z-slices) ----
    gemm_mfma<64, 0, false><<<dim3(64, 1, 4), 256, 0, stream>>>(
        x_h2 + 15l*128*4096, 4096, 2048, unwih_h2, 4096, 2048, nullptr,
        part, 4096, 4096, 512, 524288);                                // -> B
    reduce4_bias<<<512, 256, 0, stream>>>(part, unb, ugate);  // transposed out

    // ---- xgates = x @ roll_wih^T + rollb (transposed layout, into E) ----
    gemm_mfma<128, 2, true><<<dim3(32, 16, 1), 256, 0, stream>>>(
        x_h2, 4096, 2048, wihr_h2, 4096, 2048, rollb, xgates, 4096, 4096, 2048, 0);

    // ---- conversions wave 3: un_whh (into C), cls_w (into B+8MiB) ----
    convert_multi<<<5096, 256, 0, stream>>>(
        un_whh, unwhh_h2, 1048576, 8,
        cls_w,  clsw_h2,  256000,  8,
        nullptr, nullptr, 0, 0, nullptr, nullptr, 0, 0,
        nullptr, nullptr, nullptr, nullptr, nullptr, nullptr, 0);

    // ---- fused recurrence: 16 roll + 2 unroll steps ----
    lstm_persistent<<<NBLK, 512, 0, stream>>>(whhr_h2, unwhh_h2,
                                              xgates, ugate, hbufs, h_h2, barctr);

    // ---- classifier + head ----
    gemm_mfma<64, 0, true><<<dim3(16, 1, 1), 256, 0, stream>>>(
        h_h2, 2048, 1024, clsw_h2, 2048, 1024, cls_b, out, 1000, 1000, 1024, 0);
    head_kernel<<<128, 256, 0, stream>>>(out, act, out, lossbuf);
    loss_reduce<<<1, 128, 0, stream>>>(lossbuf, out);
}

// Round 12
// 585.709 us; speedup vs baseline: 2.3076x; 1.0118x over previous
//
#include <hip/hip_runtime.h>
#include <math.h>

// S=16, B=128, FEAT=2048, HAND=63, H=1024, C=1000
// out depends only on t=S-1 => 2 unroll steps from (hs[15], cs[15]).
// gates(t) = [x_t @ wih^T + bih + bhh] (hoisted) + h @ whh^T
// Precision: double-f16 operands (hi+lo); GEMMs accumulate 3 segments
// (Ahi*Whi + Alo*Whi + Ahi*Wlo) in f32. Recurrence drops the h-lo segment
// (h in [-1,1]) but keeps W hi+lo.
// Recurrence coherence model (validated rounds 6-8): h(t) -> FRESH buffer per
// step via sc1 relaxed atomic stores (land at LLC); readers use coalesced
// global_load_lds (fresh addresses never stale within a dispatch;
// dispatch-boundary invalidation covers graph replays). Flags via sc1.

typedef __attribute__((ext_vector_type(8))) _Float16 f16x8;
typedef __attribute__((ext_vector_type(4))) _Float16 f16x4;
typedef __attribute__((ext_vector_type(4))) float     f32x4;

typedef __attribute__((address_space(1))) const void as1c_void;
typedef __attribute__((address_space(3))) void       as3_void;
#define GLOAD_LDS16(g, l) \
    __builtin_amdgcn_global_load_lds((as1c_void*)(g), (as3_void*)(l), 16, 0, 0)

#define NBLK 256   // persistent blocks: 1 per CU (128KB LDS forces it)

// ---------------------------------------------------------------------------
// MFMA GEMM, 3-segment double-f16. A: [M][lda] split rows (lo at +aLoOff).
// W: [N][ldw] split rows (lo at +wLoOff). BM=128, BK=64, 4 waves (2x2).
// LDS XOR-swizzle byte^=((row&7)<<4) via pre-swizzled source address.
// grid.z = K-split slice of ksize; partial out at Cf + z*cOffPerZ.
// OUTMODE: 0 = f32 row-major; 1 = f16 split (hi at col, lo at col+ldc/2);
//          2 = f32 xg-transposed [t][jgroup][b][jj][q] (t=row>>7,b=row&127).
// ---------------------------------------------------------------------------
template<int BN, int OUTMODE, bool BIAS>
__global__ __launch_bounds__(256)
void gemm_mfma(const _Float16* __restrict__ A, int lda, int aLoOff,
               const _Float16* __restrict__ W, int ldw, int wLoOff,
               const float* __restrict__ bias,
               void* __restrict__ Cout, int ldc, int Nout,
               int ksize, long cOffPerZ)
{
    constexpr int BM = 128, BK = 64;
    constexpr int WTN = BN / 2;
    constexpr int NF  = WTN / 16;

    __shared__ _Float16 As[BM * BK];
    __shared__ _Float16 Ws[BN * BK];

    const int tid  = threadIdx.x;
    const int wave = tid >> 6, lane = tid & 63;
    const int wr = wave >> 1, wc = wave & 1;
    const int bn = blockIdx.x * BN;
    const int bm = blockIdx.y * BM;
    const long kbase = (long)blockIdx.z * ksize;

    f32x4 acc[4][NF];
    #pragma unroll
    for (int i = 0; i < 4; ++i)
        #pragma unroll
        for (int j = 0; j < NF; ++j) acc[i][j] = (f32x4){0.f, 0.f, 0.f, 0.f};

    const int srow  = tid >> 3;          // 0..31
    const int sbyte = (tid & 7) * 16;
    const int swzS  = (srow & 7) << 4;

    const int arow0 = wr * 64 + (lane & 15);
    const int abyte = (lane >> 4) * 16;

    for (int seg = 0; seg < 3; ++seg) {
        const int aOff = (seg == 1) ? aLoOff : 0;
        const int wOff = (seg == 2) ? wLoOff : 0;

        for (int k0 = 0; k0 < ksize; k0 += BK) {
            const long kg = kbase + k0;
            #pragma unroll
            for (int r = 0; r < 4; ++r) {
                const _Float16* src = A + ((long)(bm + 32*r + srow) * lda
                                           + aOff + kg) + ((sbyte ^ swzS) >> 1);
                GLOAD_LDS16(src, (char*)As + r*4096 + wave*1024);
            }
            #pragma unroll
            for (int r = 0; r < BN/32; ++r) {
                const _Float16* src = W + ((long)(bn + 32*r + srow) * ldw
                                           + wOff + kg) + ((sbyte ^ swzS) >> 1);
                GLOAD_LDS16(src, (char*)Ws + r*4096 + wave*1024);
            }
            __syncthreads();
            #pragma unroll
            for (int kk = 0; kk < 2; ++kk) {
                f16x8 af[4], bfr[NF];
                #pragma unroll
                for (int mi = 0; mi < 4; ++mi) {
                    const int row = arow0 + mi*16;
                    const int byi = (kk*64 + abyte) ^ ((row & 7) << 4);
                    af[mi] = *(const f16x8*)((const char*)As + row*128 + byi);
                }
                #pragma unroll
                for (int ni = 0; ni < NF; ++ni) {
                    const int row = wc*WTN + ni*16 + (lane & 15);
                    const int byi = (kk*64 + abyte) ^ ((row & 7) << 4);
                    bfr[ni] = *(const f16x8*)((const char*)Ws + row*128 + byi);
                }
                #pragma unroll
                for (int mi = 0; mi < 4; ++mi)
                    #pragma unroll
                    for (int ni = 0; ni < NF; ++ni)
                        acc[mi][ni] = __builtin_amdgcn_mfma_f32_16x16x32_f16(
                            af[mi], bfr[ni], acc[mi][ni], 0, 0, 0);
            }
            __syncthreads();
        }
    }

    float*     Cf = (float*)Cout + blockIdx.z * cOffPerZ;
    _Float16*  Ch = (_Float16*)Cout;
    #pragma unroll
    for (int mi = 0; mi < 4; ++mi) {
        #pragma unroll
        for (int ni = 0; ni < NF; ++ni) {
            const int col = bn + wc*WTN + ni*16 + (lane & 15);
            if (col < Nout) {
                const float bv = BIAS ? bias[col] : 0.f;
                #pragma unroll
                for (int r = 0; r < 4; ++r) {
                    const int row = bm + wr*64 + mi*16 + (lane >> 4)*4 + r;
                    const float v = acc[mi][ni][r] + bv;
                    if constexpr (OUTMODE == 1) {
                        _Float16 hi = (_Float16)v;
                        Ch[(long)row * ldc + col]         = hi;
                        Ch[(long)row * ldc + ldc/2 + col] = (_Float16)(v - (float)hi);
                    } else if constexpr (OUTMODE == 2) {
                        const int t = row >> 7, b = row & 127;
                        const int q = col >> 10, j = col & 1023;
                        Cf[(long)t*524288 + (long)(j>>2)*2048
                           + b*16 + (j&3)*4 + q] = v;
                    } else {
                        Cf[(long)row * ldc + col] = v;
                    }
                }
            }
        }
    }
}

// ---------------------------------------------------------------------------
// Persistent fused LSTM v4 (round-7 proven): 16 roll + 2 unroll steps, one
// dispatch. 256 blocks x 512 threads, 1 block/CU (128KB LDS). Block owns 4
// h-cols (16 gate cols); whh slice [hi|lo] LDS-resident (64KB). Per step:
// h(t-1) (256KB, hi only) staged via coalesced global_load_lds in 8 chunks
// of K=128, double-buffered, counted vmcnt. h(t) to a fresh buffer via
// packed sc1 u64 stores. Flat wave-parallel flag barrier.
// ---------------------------------------------------------------------------
__global__ __launch_bounds__(512)
void lstm_persistent(const _Float16* __restrict__ whh,
                     const _Float16* __restrict__ uwhh,
                     const float* __restrict__ xgT,
                     const float* __restrict__ ugT,
                     _Float16* __restrict__ hbufs,   // 17 x 131072 (hi only)
                     _Float16* __restrict__ hfin,    // [128][2048] hi|lo
                     unsigned* __restrict__ bar)
{
    __shared__ alignas(16) _Float16 Wl[16 * 2048];     // 64KB
    __shared__ alignas(16) _Float16 As[2][128 * 128];  // 2 x 32KB
    float* Gl = (float*)&As[0][0];                     // 8KB overlay (post-mma)

    const int tid  = threadIdx.x;
    const int wave = tid >> 6, lane = tid & 63;
    const int bid  = (int)blockIdx.x;
    const int j0   = bid * 4;            // owned h-cols

    // flat barrier: store own flag; wave 0 polls all 256 flags in parallel
    auto grid_barrier = [&](unsigned ph) {
        __syncthreads();                 // drains all waves' vmcnt (h stores)
        if (wave == 0) {
            if (lane == 0)
                __hip_atomic_store(bar + bid, ph, __ATOMIC_RELAXED,
                                   __HIP_MEMORY_SCOPE_AGENT);
            const unsigned long long* b64 = (const unsigned long long*)bar;
            for (;;) {
                unsigned long long a = __hip_atomic_load(b64 + lane,
                    __ATOMIC_RELAXED, __HIP_MEMORY_SCOPE_AGENT);
                unsigned long long c = __hip_atomic_load(b64 + 64 + lane,
                    __ATOMIC_RELAXED, __HIP_MEMORY_SCOPE_AGENT);
                const int ok = ((unsigned)a >= ph) && ((unsigned)(a >> 32) >= ph)
                            && ((unsigned)c >= ph) && ((unsigned)(c >> 32) >= ph);
                if (__all(ok)) break;
                __builtin_amdgcn_s_sleep(1);
            }
        }
        __syncthreads();
    };

    auto stageW = [&](const _Float16* __restrict__ src) {
        const int byte = (tid & 255) * 16;
        #pragma unroll
        for (int it = 0; it < 8; ++it) {
            const int g = it * 2 + (wave >> 2);
            const long G = (long)(g >> 2) * 1024 + j0 + (g & 3);
            const _Float16* s = src + G * 2048 + ((byte ^ ((g & 7) << 4)) >> 1);
            GLOAD_LDS16(s, (char*)Wl + g * 4096 + (wave & 3) * 1024);
        }
    };

    const int b_c = tid >> 2;            // cell: batch row 0..127
    const int jj  = tid & 3;             // cell: col within owned 4
    float c_reg = 0.f;

    auto do_cell = [&](float4 xgv, bool addGl, _Float16* hout, bool fin) {
        float g4[4] = {xgv.x, xgv.y, xgv.z, xgv.w};
        if (addGl) {
            #pragma unroll
            for (int q = 0; q < 4; ++q) g4[q] += Gl[b_c * 16 + q * 4 + jj];
        }
        const float si = 1.f / (1.f + __expf(-g4[0]));
        const float sf = 1.f / (1.f + __expf(-g4[1]));
        const float so = 1.f / (1.f + __expf(-g4[3]));
        float e = __expf(-2.f * fabsf(g4[2]));
        float tg = (1.f - e) / (1.f + e); tg = g4[2] < 0.f ? -tg : tg;
        c_reg = sf * c_reg + si * tg;
        e = __expf(-2.f * fabsf(c_reg));
        float tc = (1.f - e) / (1.f + e); tc = c_reg < 0.f ? -tc : tc;
        const float hv = so * tc;
        union { _Float16 f; unsigned short u; } cv; cv.f = (_Float16)hv;
        if (fin) {                       // final step: plain stores, hi + lo
            hout[(long)b_c * 2048 + j0 + jj]        = cv.f;
            hout[(long)b_c * 2048 + 1024 + j0 + jj] = (_Float16)(hv - (float)cv.f);
        } else {                         // pack 4 cols -> one 8B sc1 store
            int w  = cv.u;
            int p2 = w | (__shfl_xor(w, 1) << 16);
            int q2 = __shfl_xor(p2, 2);
            if (jj == 0) {
                unsigned long long v = (unsigned)p2
                                     | ((unsigned long long)(unsigned)q2 << 32);
                __hip_atomic_store((unsigned long long*)(hout + (long)b_c*1024 + j0),
                                   v, __ATOMIC_RELAXED, __HIP_MEMORY_SCOPE_AGENT);
            }
        }
    };

    stageW(whh);   // drained by grid_barrier(1)'s syncthreads

    // ---- step 0: h == 0 -> gates = xg[0] ----
    const long xoff = (long)bid * 2048 + b_c * 16 + jj * 4;
    { float4 x0 = *(const float4*)(xgT + xoff); do_cell(x0, false, hbufs, false); }
    grid_barrier(1);

    // staging geometry: thread covers (row = pass*32 + wave*4 + (lane>>4)),
    // 16B at byte (lane&15)*16 of the 256B chunk-row; LDS dest linear.
    const int srow_w = wave * 4 + (lane >> 4);
    const int sb     = (lane & 15) * 16;
    // MFMA fragment geometry
    const int arow = wave * 16 + (lane & 15);          // batch row
    const int aswz = (arow & 7) << 4;
    const char* wrow = (const char*)Wl + (lane & 15) * 4096;
    const int wswz = (lane & 7) << 4;                  // ((g&7)<<4), g=lane&15

    for (int p = 1; p < 18; ++p) {
        if (p == 16) {                   // swap in unroll weights
            stageW(uwhh);
            asm volatile("s_waitcnt vmcnt(0)" ::: "memory");
            __syncthreads();
        }
        const float* xsrc = (p <= 15) ? xgT + (long)p * 524288 : ugT;
        float4 xcur = *(const float4*)(xsrc + xoff);
        const _Float16* hprev = hbufs + (long)(p - 1) * 131072;

        auto issue = [&](int ck, int buf) {
            #pragma unroll
            for (int pass = 0; pass < 4; ++pass) {
                const int row = pass * 32 + srow_w;
                const _Float16* src = hprev + (long)row * 1024 + ck * 128
                                    + ((sb ^ ((row & 7) << 4)) >> 1);
                GLOAD_LDS16(src, (char*)&As[buf][0] + pass*8192 + wave*1024);
            }
        };
        issue(0, 0);

        f32x4 acc = (f32x4){0.f, 0.f, 0.f, 0.f};
        for (int ck = 0; ck < 8; ++ck) {
            __builtin_amdgcn_s_barrier();            // prev mma done everywhere
            if (ck < 7) {
                issue(ck + 1, (ck + 1) & 1);
                asm volatile("s_waitcnt vmcnt(4)" ::: "memory");  // ck landed
            } else {
                asm volatile("s_waitcnt vmcnt(0)" ::: "memory");
            }
            __builtin_amdgcn_s_barrier();            // chunk ck visible to all
            const char* abase = (const char*)&As[ck & 1][0] + arow * 256;
            #pragma unroll
            for (int kb = 0; kb < 4; ++kb) {
                const int ab = kb * 64 + ((lane >> 4) << 4);
                const f16x8 a   = *(const f16x8*)(abase + (ab ^ aswz));
                const int  wb  = ck * 256 + ab;
                const f16x8 bhi = *(const f16x8*)(wrow + ((wb ^ wswz)));
                const f16x8 blo = *(const f16x8*)(wrow + 2048 + ((wb ^ wswz)));
                acc = __builtin_amdgcn_mfma_f32_16x16x32_f16(a, bhi, acc, 0, 0, 0);
                acc = __builtin_amdgcn_mfma_f32_16x16x32_f16(a, blo, acc, 0, 0, 0);
            }
        }
        __syncthreads();                 // all mma done -> Gl overlay safe
        #pragma unroll
        for (int r = 0; r < 4; ++r)
            Gl[(wave * 16 + (lane >> 4) * 4 + r) * 16 + (lane & 15)] = acc[r];
        __syncthreads();

        do_cell(xcur, true,
                (p == 17) ? hfin : hbufs + (long)p * 131072, p == 17);
        if (p < 17) grid_barrier(p + 1);
    }
}

// ---------------------------------------------------------------------------
// Fused multi-tensor f32 -> split-f16 convert (rows [hi(K)|lo(K)]) + bias
// sums. Up to 4 ranges (n in float4 units, sh = log2(K/4)); bias range last.
// ---------------------------------------------------------------------------
__global__ __launch_bounds__(256)
void convert_multi(const float* __restrict__ s0, _Float16* __restrict__ d0, long n0, int sh0,
                   const float* __restrict__ s1, _Float16* __restrict__ d1, long n1, int sh1,
                   const float* __restrict__ s2, _Float16* __restrict__ d2, long n2, int sh2,
                   const float* __restrict__ s3, _Float16* __restrict__ d3, long n3, int sh3,
                   const float* __restrict__ ba1, const float* __restrict__ bb1,
                   const float* __restrict__ ba2, const float* __restrict__ bb2,
                   float* __restrict__ o1, float* __restrict__ o2, long nb4)
{
    long i = (long)blockIdx.x * 256 + threadIdx.x;
    const float* s; _Float16* d; int sh;
    if (i < n0)      { s = s0; d = d0; sh = sh0; }
    else { i -= n0;
    if (i < n1)      { s = s1; d = d1; sh = sh1; }
    else { i -= n1;
    if (i < n2)      { s = s2; d = d2; sh = sh2; }
    else { i -= n2;
    if (i < n3)      { s = s3; d = d3; sh = sh3; }
    else { i -= n3;
        if (i >= nb4) return;
        const long half = nb4 >> 1;
        const bool first = (i < half);
        const long k = first ? i : (i - half);
        const float4 a = ((const float4*)(first ? ba1 : ba2))[k];
        const float4 b = ((const float4*)(first ? bb1 : bb2))[k];
        float4 r; r.x = a.x + b.x; r.y = a.y + b.y;
                  r.z = a.z + b.z; r.w = a.w + b.w;
        ((float4*)(first ? o1 : o2))[k] = r;
        return;
    }}}}
    const long row = i >> sh;
    const long k4  = i & ((1L << sh) - 1);
    const float4 v = ((const float4*)s)[i];
    const float vv[4] = {v.x, v.y, v.z, v.w};
    f16x4 hi, lo;
    #pragma unroll
    for (int j = 0; j < 4; ++j) {
        hi[j] = (_Float16)vv[j];
        lo[j] = (_Float16)(vv[j] - (float)hi[j]);
    }
    ((f16x4*)d)[(row << (sh + 1)) + k4]              = hi;
    ((f16x4*)d)[(row << (sh + 1)) + (1L << sh) + k4] = lo;
}

// ---------------------------------------------------------------------------
// hproj: x[:, 1024:2048] = concat(lh,rh) @ fch_w^T + fch_b (K=126), split out.
// ---------------------------------------------------------------------------
__global__ __launch_bounds__(256)
void hproj_kernel(const float* __restrict__ lh, const float* __restrict__ rh,
                  const float* __restrict__ fchw, const float* __restrict__ fchb,
                  _Float16* __restrict__ x)
{
    __shared__ float hs[16][126];
    const int brow = blockIdx.x * 16;
    for (int idx = threadIdx.x; idx < 16 * 126; idx += 256) {
        const int r = idx / 126, k = idx % 126;
        const int grow = brow + r;
        hs[r][k] = (k < 63) ? lh[(long)grow * 63 + k]
                            : rh[(long)grow * 63 + (k - 63)];
    }
    __syncthreads();
    for (int j = threadIdx.x; j < 1024; j += 256) {
        float acc[16];
        #pragma unroll
        for (int r = 0; r < 16; ++r) acc[r] = 0.f;
        const float* wrow = fchw + (long)j * 126;
        for (int k = 0; k < 126; ++k) {
            const float w = wrow[k];
            #pragma unroll
            for (int r = 0; r < 16; ++r) acc[r] = fmaf(w, hs[r][k], acc[r]);
        }
        const float b = fchb[j];
        #pragma unroll
        for (int r = 0; r < 16; ++r) {
            const float v = acc[r] + b;
            const _Float16 hi = (_Float16)v;
            x[(long)(brow + r) * 4096 + 1024 + j] = hi;
            x[(long)(brow + r) * 4096 + 3072 + j] = (_Float16)(v - (float)hi);
        }
    }
}

// ugate = sum of 4 K-split partials + bias, output in xg-transposed layout.
__global__ __launch_bounds__(256)
void reduce4_bias(const float* __restrict__ part, const float* __restrict__ bias,
                  float* __restrict__ out)
{
    const int t = blockIdx.x * 256 + threadIdx.x;
    const long o = (long)t * 4;
    const int b   = (int)(o >> 12);
    const int rem = (int)(o & 4095);
    const int q   = rem >> 10, jb = rem & 1023;
    float4 s = *(const float4*)(part + o);
    #pragma unroll
    for (int p = 1; p < 4; ++p) {
        const float4 v = *(const float4*)(part + (long)p*524288 + o);
        s.x += v.x; s.y += v.y; s.z += v.z; s.w += v.w;
    }
    const float4 bb = *(const float4*)(bias + rem);
    const float sv[4] = {s.x + bb.x, s.y + bb.y, s.z + bb.z, s.w + bb.w};
    #pragma unroll
    for (int e = 0; e < 4; ++e) {
        const int j = jb + e;
        out[(long)(j >> 2) * 2048 + b * 16 + (j & 3) * 4 + q] = sv[e];
    }
}

// ---------------------------------------------------------------------------
// Head: per-row argmax (first-max tie-break) + logsumexp + per-row loss.
// ---------------------------------------------------------------------------
__global__ __launch_bounds__(256)
void head_kernel(const float* __restrict__ logits, const int* __restrict__ act,
                 float* __restrict__ d_out, float* __restrict__ lossbuf)
{
    const int b = blockIdx.x;
    const int tid = threadIdx.x;
    const float* row = logits + (long)b * 1000;

    float mx = -1e30f; int mi = 1 << 30;
    for (int j = tid; j < 1000; j += 256) {
        const float v = row[j];
        if (v > mx) { mx = v; mi = j; }
    }
    __shared__ float smx[256];
    __shared__ int   smi[256];
    smx[tid] = mx; smi[tid] = mi;
    __syncthreads();
    for (int s = 128; s > 0; s >>= 1) {
        if (tid < s) {
            const float v2 = smx[tid + s]; const int i2 = smi[tid + s];
            if (v2 > smx[tid] || (v2 == smx[tid] && i2 < smi[tid])) {
                smx[tid] = v2; smi[tid] = i2;
            }
        }
        __syncthreads();
    }
    const float gmx = smx[0];
    const int   gmi = smi[0];
    __syncthreads();

    float partial = 0.f;
    for (int j = tid; j < 1000; j += 256) partial += __expf(row[j] - gmx);
    smx[tid] = partial;
    __syncthreads();
    for (int s = 128; s > 0; s >>= 1) {
        if (tid < s) smx[tid] += smx[tid + s];
        __syncthreads();
    }
    if (tid == 0) {
        d_out[128000 + b] = (float)gmi;
        lossbuf[b] = gmx + logf(smx[0]) - row[act[b]];
    }
}

__global__ __launch_bounds__(128)
void loss_reduce(const float* __restrict__ lossbuf, float* __restrict__ d_out)
{
    __shared__ float s[128];
    const int tid = threadIdx.x;
    s[tid] = lossbuf[tid];
    __syncthreads();
    for (int k = 64; k > 0; k >>= 1) {
        if (tid < k) s[tid] += s[tid + k];
        __syncthreads();
    }
    if (tid == 0) d_out[128128] = s[0] / 128.f;
}

// ---------------------------------------------------------------------------
extern "C" void kernel_launch(void* const* d_in, const int* in_sizes, int n_in,
                              void* d_out, int out_size, void* d_ws, size_t ws_size,
                              hipStream_t stream)
{
    const float* feats    = (const float*)d_in[0];
    const float* lh       = (const float*)d_in[1];
    const float* rh       = (const float*)d_in[2];
    const int*   act      = (const int*)  d_in[3];
    const float* fc1_w    = (const float*)d_in[4];
    const float* fc1_b    = (const float*)d_in[5];
    const float* fch_w    = (const float*)d_in[6];
    const float* fch_b    = (const float*)d_in[7];
    const float* roll_wih = (const float*)d_in[8];
    const float* roll_whh = (const float*)d_in[9];
    const float* roll_bih = (const float*)d_in[10];
    const float* roll_bhh = (const float*)d_in[11];
    const float* un_wih   = (const float*)d_in[12];
    const float* un_whh   = (const float*)d_in[13];
    const float* un_bih   = (const float*)d_in[14];
    const float* un_bhh   = (const float*)d_in[15];
    const float* cls_w    = (const float*)d_in[16];
    const float* cls_b    = (const float*)d_in[17];

    float* out = (float*)d_out;
    char* ws = (char*)d_ws;
    size_t o = 0;
    auto alloc = [&](size_t b) { size_t r = o; o += (b + 255) & ~(size_t)255; return r; };

    // regions (temporal aliasing documented inline)
    _Float16* x_h2     = (_Float16*)(ws + alloc(2048ul*4096*2));   // A: x split, 16MiB
    char*     regB     = ws + alloc(2048ul*4096*2);                // B: 16MiB
    char*     regC     = ws + alloc(4096ul*4096*2);                // C: 32MiB
    _Float16* whhr_h2  = (_Float16*)(ws + alloc(4096ul*2048*2));   // D: 16MiB
    char*     regE     = ws + alloc(16ul*128*4096*4);              // E: 32MiB
    float*    ugate    = (float*)   (ws + alloc(128ul*4096*4));    // F: 2MiB
    _Float16* h_h2     = (_Float16*)(ws + alloc(128ul*2048*2));    // G: 512KiB
    float*    rollb    = (float*)   (ws + alloc(4096*4));
    float*    unb      = (float*)   (ws + alloc(4096*4));
    float*    lossbuf  = (float*)   (ws + alloc(128*4));
    unsigned* barctr   = (unsigned*)(ws + alloc(2048));

    _Float16* feats_h2 = (_Float16*)regB;                 // dead after xproj
    float*    part     = (float*)regB;                    // ugate partials (8MiB)
    _Float16* clsw_h2  = (_Float16*)(regB + (8ul<<20));   // 4MiB, after part dead
    _Float16* wihr_h2  = (_Float16*)regC;                 // dead after xgates
    _Float16* unwhh_h2 = (_Float16*)regC;                 // after xgates (16MiB)
    _Float16* hbufs    = (_Float16*)(regC + (16ul<<20));  // 17x256KB, after xgates
    _Float16* fc1w_h2  = (_Float16*)regE;                 // dead after xproj
    _Float16* unwih_h2 = (_Float16*)regE;                 // after xproj, dead after ugate
    float*    xgates   = (float*)regE;                    // after ugate (transposed)

    // ---- conversions wave 1: feats, roll_wih, roll_whh, fc1_w + biases ----
    // ranges (float4): 1048576 + 2097152 + 1048576 + 524288 + 2048 = 4720640
    convert_multi<<<18440, 256, 0, stream>>>(
        feats,    feats_h2, 1048576, 9,
        roll_wih, wihr_h2,  2097152, 9,
        roll_whh, whhr_h2,  1048576, 8,
        fc1_w,    fc1w_h2,  524288,  9,
        roll_bih, roll_bhh, un_bih, un_bhh, rollb, unb, 2048);
    hipMemsetAsync(barctr, 0, 2048, stream);

    // ---- x = [xproj | hproj] ----
    gemm_mfma<64, 1, true><<<dim3(16, 16, 1), 256, 0, stream>>>(
        feats_h2, 4096, 2048, fc1w_h2, 4096, 2048, fc1_b,
        x_h2, 4096, 1024, 2048, 0);
    hproj_kernel<<<128, 256, 0, stream>>>(lh, rh, fch_w, fch_b, x_h2);

    // ---- conversions wave 2: un_wih (into E, after xproj freed fc1w) ----
    convert_multi<<<8192, 256, 0, stream>>>(
        un_wih, unwih_h2, 2097152, 9,
        nullptr, nullptr, 0, 0, nullptr, nullptr, 0, 0, nullptr, nullptr, 0, 0,
        nullptr, nullptr, nullptr, nullptr, nullptr, nullptr, 0);

    // ---- ugate = x[15] @ un_wih^T + unb (K=2048 split over 4 z-slices) ----
    gemm_mfma<64, 0, false><<<dim3(64, 1, 4), 256, 0, stream>>>(
        x_h2 + 15l*128*4096, 4096, 2048, unwih_h2, 4096, 2048, nullptr,
        part, 4096, 4096, 512, 524288);                                // -> B
    reduce4_bias<<<512, 256, 0, stream>>>(part, unb, ugate);  // transposed out

    // ---- xgates = x @ roll_wih^T + rollb (transposed layout, into E) ----
    gemm_mfma<128, 2, true><<<dim3(32, 16, 1), 256, 0, stream>>>(
        x_h2, 4096, 2048, wihr_h2, 4096, 2048, rollb, xgates, 4096, 4096, 2048, 0);

    // ---- conversions wave 3: un_whh (into C), cls_w (into B+8MiB) ----
    convert_multi<<<5096, 256, 0, stream>>>(
        un_whh, unwhh_h2, 1048576, 8,
        cls_w,  clsw_h2,  256000,  8,
        nullptr, nullptr, 0, 0, nullptr, nullptr, 0, 0,
        nullptr, nullptr, nullptr, nullptr, nullptr, nullptr, 0);

    // ---- fused recurrence: 16 roll + 2 unroll steps ----
    lstm_persistent<<<NBLK, 512, 0, stream>>>(whhr_h2, unwhh_h2,
                                              xgates, ugate, hbufs, h_h2, barctr);

    // ---- classifier + head ----
    gemm_mfma<64, 0, true><<<dim3(16, 1, 1), 256, 0, stream>>>(
        h_h2, 2048, 1024, clsw_h2, 2048, 1024, cls_b, out, 1000, 1000, 1024, 0);
    head_kernel<<<128, 256, 0, stream>>>(out, act, out, lossbuf);
    loss_reduce<<<1, 128, 0, stream>>>(lossbuf, out);
}

// Round 13
// 584.873 us; speedup vs baseline: 2.3109x; 1.0014x over previous
//
#include <hip/hip_runtime.h>
#include <math.h>

// S=16, B=128, FEAT=2048, HAND=63, H=1024, C=1000
// out depends only on t=S-1 => 2 unroll steps from (hs[15], cs[15]).
// gates(t) = [x_t @ wih^T + bih + bhh] (hoisted) + h @ whh^T
// Precision: double-f16 operands (hi+lo); GEMMs accumulate 3 segments
// (Ahi*Whi + Alo*Whi + Ahi*Wlo) in f32. Recurrence drops the h-lo segment
// (h in [-1,1]) but keeps W hi+lo.
// Recurrence coherence model (validated rounds 6-8): h(t) -> FRESH buffer per
// step via sc1 relaxed atomic stores (land at LLC); readers use coalesced
// global_load_lds (fresh addresses never stale within a dispatch;
// dispatch-boundary invalidation covers graph replays). Flags via sc1.

typedef __attribute__((ext_vector_type(8))) _Float16 f16x8;
typedef __attribute__((ext_vector_type(4))) _Float16 f16x4;
typedef __attribute__((ext_vector_type(4))) float     f32x4;

typedef __attribute__((address_space(1))) const void as1c_void;
typedef __attribute__((address_space(3))) void       as3_void;
#define GLOAD_LDS16(g, l) \
    __builtin_amdgcn_global_load_lds((as1c_void*)(g), (as3_void*)(l), 16, 0, 0)

#define NBLK 256   // persistent blocks: 1 per CU (128KB LDS forces it)

// ---------------------------------------------------------------------------
// MFMA GEMM, 3-segment double-f16. A: [M][lda] split rows (lo at +aLoOff).
// W: [N][ldw] split rows (lo at +wLoOff). BM=128, BK=64, 4 waves (2x2).
// LDS XOR-swizzle byte^=((row&7)<<4) via pre-swizzled source address.
// grid.z = K-split slice of ksize; partial out at Cf + z*cOffPerZ.
// OUTMODE: 0 = f32 row-major; 1 = f16 split (hi at col, lo at col+ldc/2);
//          2 = f32 xg-transposed [t][jgroup][b][jj][q] (t=row>>7,b=row&127).
// ---------------------------------------------------------------------------
template<int BN, int OUTMODE, bool BIAS>
__global__ __launch_bounds__(256)
void gemm_mfma(const _Float16* __restrict__ A, int lda, int aLoOff,
               const _Float16* __restrict__ W, int ldw, int wLoOff,
               const float* __restrict__ bias,
               void* __restrict__ Cout, int ldc, int Nout,
               int ksize, long cOffPerZ)
{
    constexpr int BM = 128, BK = 64;
    constexpr int WTN = BN / 2;
    constexpr int NF  = WTN / 16;

    __shared__ _Float16 As[BM * BK];
    __shared__ _Float16 Ws[BN * BK];

    const int tid  = threadIdx.x;
    const int wave = tid >> 6, lane = tid & 63;
    const int wr = wave >> 1, wc = wave & 1;
    const int bn = blockIdx.x * BN;
    const int bm = blockIdx.y * BM;
    const long kbase = (long)blockIdx.z * ksize;

    f32x4 acc[4][NF];
    #pragma unroll
    for (int i = 0; i < 4; ++i)
        #pragma unroll
        for (int j = 0; j < NF; ++j) acc[i][j] = (f32x4){0.f, 0.f, 0.f, 0.f};

    const int srow  = tid >> 3;          // 0..31
    const int sbyte = (tid & 7) * 16;
    const int swzS  = (srow & 7) << 4;

    const int arow0 = wr * 64 + (lane & 15);
    const int abyte = (lane >> 4) * 16;

    for (int seg = 0; seg < 3; ++seg) {
        const int aOff = (seg == 1) ? aLoOff : 0;
        const int wOff = (seg == 2) ? wLoOff : 0;

        for (int k0 = 0; k0 < ksize; k0 += BK) {
            const long kg = kbase + k0;
            #pragma unroll
            for (int r = 0; r < 4; ++r) {
                const _Float16* src = A + ((long)(bm + 32*r + srow) * lda
                                           + aOff + kg) + ((sbyte ^ swzS) >> 1);
                GLOAD_LDS16(src, (char*)As + r*4096 + wave*1024);
            }
            #pragma unroll
            for (int r = 0; r < BN/32; ++r) {
                const _Float16* src = W + ((long)(bn + 32*r + srow) * ldw
                                           + wOff + kg) + ((sbyte ^ swzS) >> 1);
                GLOAD_LDS16(src, (char*)Ws + r*4096 + wave*1024);
            }
            __syncthreads();
            #pragma unroll
            for (int kk = 0; kk < 2; ++kk) {
                f16x8 af[4], bfr[NF];
                #pragma unroll
                for (int mi = 0; mi < 4; ++mi) {
                    const int row = arow0 + mi*16;
                    const int byi = (kk*64 + abyte) ^ ((row & 7) << 4);
                    af[mi] = *(const f16x8*)((const char*)As + row*128 + byi);
                }
                #pragma unroll
                for (int ni = 0; ni < NF; ++ni) {
                    const int row = wc*WTN + ni*16 + (lane & 15);
                    const int byi = (kk*64 + abyte) ^ ((row & 7) << 4);
                    bfr[ni] = *(const f16x8*)((const char*)Ws + row*128 + byi);
                }
                #pragma unroll
                for (int mi = 0; mi < 4; ++mi)
                    #pragma unroll
                    for (int ni = 0; ni < NF; ++ni)
                        acc[mi][ni] = __builtin_amdgcn_mfma_f32_16x16x32_f16(
                            af[mi], bfr[ni], acc[mi][ni], 0, 0, 0);
            }
            __syncthreads();
        }
    }

    float*     Cf = (float*)Cout + blockIdx.z * cOffPerZ;
    _Float16*  Ch = (_Float16*)Cout;
    #pragma unroll
    for (int mi = 0; mi < 4; ++mi) {
        #pragma unroll
        for (int ni = 0; ni < NF; ++ni) {
            const int col = bn + wc*WTN + ni*16 + (lane & 15);
            if (col < Nout) {
                const float bv = BIAS ? bias[col] : 0.f;
                #pragma unroll
                for (int r = 0; r < 4; ++r) {
                    const int row = bm + wr*64 + mi*16 + (lane >> 4)*4 + r;
                    const float v = acc[mi][ni][r] + bv;
                    if constexpr (OUTMODE == 1) {
                        _Float16 hi = (_Float16)v;
                        Ch[(long)row * ldc + col]         = hi;
                        Ch[(long)row * ldc + ldc/2 + col] = (_Float16)(v - (float)hi);
                    } else if constexpr (OUTMODE == 2) {
                        const int t = row >> 7, b = row & 127;
                        const int q = col >> 10, j = col & 1023;
                        Cf[(long)t*524288 + (long)(j>>2)*2048
                           + b*16 + (j&3)*4 + q] = v;
                    } else {
                        Cf[(long)row * ldc + col] = v;
                    }
                }
            }
        }
    }
}

// ---------------------------------------------------------------------------
// Persistent fused LSTM v4 (round-7 proven): 16 roll + 2 unroll steps, one
// dispatch. 256 blocks x 512 threads, 1 block/CU (128KB LDS). Block owns 4
// h-cols (16 gate cols); whh slice [hi|lo] LDS-resident (64KB). Per step:
// h(t-1) (256KB, hi only) staged via coalesced global_load_lds in 8 chunks
// of K=128, double-buffered, counted vmcnt. h(t) to a fresh buffer via
// packed sc1 u64 stores. Flat wave-parallel flag barrier.
// ---------------------------------------------------------------------------
__global__ __launch_bounds__(512)
void lstm_persistent(const _Float16* __restrict__ whh,
                     const _Float16* __restrict__ uwhh,
                     const float* __restrict__ xgT,
                     const float* __restrict__ ugT,
                     _Float16* __restrict__ hbufs,   // 17 x 131072 (hi only)
                     _Float16* __restrict__ hfin,    // [128][2048] hi|lo
                     unsigned* __restrict__ bar)
{
    __shared__ alignas(16) _Float16 Wl[16 * 2048];     // 64KB
    __shared__ alignas(16) _Float16 As[2][128 * 128];  // 2 x 32KB
    float* Gl = (float*)&As[0][0];                     // 8KB overlay (post-mma)

    const int tid  = threadIdx.x;
    const int wave = tid >> 6, lane = tid & 63;
    const int bid  = (int)blockIdx.x;
    const int j0   = bid * 4;            // owned h-cols

    // flat barrier: store own flag; wave 0 polls all 256 flags in parallel
    auto grid_barrier = [&](unsigned ph) {
        __syncthreads();                 // drains all waves' vmcnt (h stores)
        if (wave == 0) {
            if (lane == 0)
                __hip_atomic_store(bar + bid, ph, __ATOMIC_RELAXED,
                                   __HIP_MEMORY_SCOPE_AGENT);
            const unsigned long long* b64 = (const unsigned long long*)bar;
            for (;;) {
                unsigned long long a = __hip_atomic_load(b64 + lane,
                    __ATOMIC_RELAXED, __HIP_MEMORY_SCOPE_AGENT);
                unsigned long long c = __hip_atomic_load(b64 + 64 + lane,
                    __ATOMIC_RELAXED, __HIP_MEMORY_SCOPE_AGENT);
                const int ok = ((unsigned)a >= ph) && ((unsigned)(a >> 32) >= ph)
                            && ((unsigned)c >= ph) && ((unsigned)(c >> 32) >= ph);
                if (__all(ok)) break;
                __builtin_amdgcn_s_sleep(1);
            }
        }
        __syncthreads();
    };

    auto stageW = [&](const _Float16* __restrict__ src) {
        const int byte = (tid & 255) * 16;
        #pragma unroll
        for (int it = 0; it < 8; ++it) {
            const int g = it * 2 + (wave >> 2);
            const long G = (long)(g >> 2) * 1024 + j0 + (g & 3);
            const _Float16* s = src + G * 2048 + ((byte ^ ((g & 7) << 4)) >> 1);
            GLOAD_LDS16(s, (char*)Wl + g * 4096 + (wave & 3) * 1024);
        }
    };

    const int b_c = tid >> 2;            // cell: batch row 0..127
    const int jj  = tid & 3;             // cell: col within owned 4
    float c_reg = 0.f;

    auto do_cell = [&](float4 xgv, bool addGl, _Float16* hout, bool fin) {
        float g4[4] = {xgv.x, xgv.y, xgv.z, xgv.w};
        if (addGl) {
            #pragma unroll
            for (int q = 0; q < 4; ++q) g4[q] += Gl[b_c * 16 + q * 4 + jj];
        }
        const float si = 1.f / (1.f + __expf(-g4[0]));
        const float sf = 1.f / (1.f + __expf(-g4[1]));
        const float so = 1.f / (1.f + __expf(-g4[3]));
        float e = __expf(-2.f * fabsf(g4[2]));
        float tg = (1.f - e) / (1.f + e); tg = g4[2] < 0.f ? -tg : tg;
        c_reg = sf * c_reg + si * tg;
        e = __expf(-2.f * fabsf(c_reg));
        float tc = (1.f - e) / (1.f + e); tc = c_reg < 0.f ? -tc : tc;
        const float hv = so * tc;
        union { _Float16 f; unsigned short u; } cv; cv.f = (_Float16)hv;
        if (fin) {                       // final step: plain stores, hi + lo
            hout[(long)b_c * 2048 + j0 + jj]        = cv.f;
            hout[(long)b_c * 2048 + 1024 + j0 + jj] = (_Float16)(hv - (float)cv.f);
        } else {                         // pack 4 cols -> one 8B sc1 store
            int w  = cv.u;
            int p2 = w | (__shfl_xor(w, 1) << 16);
            int q2 = __shfl_xor(p2, 2);
            if (jj == 0) {
                unsigned long long v = (unsigned)p2
                                     | ((unsigned long long)(unsigned)q2 << 32);
                __hip_atomic_store((unsigned long long*)(hout + (long)b_c*1024 + j0),
                                   v, __ATOMIC_RELAXED, __HIP_MEMORY_SCOPE_AGENT);
            }
        }
    };

    stageW(whh);   // drained by grid_barrier(1)'s syncthreads

    // ---- step 0: h == 0 -> gates = xg[0] ----
    const long xoff = (long)bid * 2048 + b_c * 16 + jj * 4;
    { float4 x0 = *(const float4*)(xgT + xoff); do_cell(x0, false, hbufs, false); }
    grid_barrier(1);

    // staging geometry: thread covers (row = pass*32 + wave*4 + (lane>>4)),
    // 16B at byte (lane&15)*16 of the 256B chunk-row; LDS dest linear.
    const int srow_w = wave * 4 + (lane >> 4);
    const int sb     = (lane & 15) * 16;
    // MFMA fragment geometry
    const int arow = wave * 16 + (lane & 15);          // batch row
    const int aswz = (arow & 7) << 4;
    const char* wrow = (const char*)Wl + (lane & 15) * 4096;
    const int wswz = (lane & 7) << 4;                  // ((g&7)<<4), g=lane&15

    for (int p = 1; p < 18; ++p) {
        if (p == 16) {                   // swap in unroll weights
            stageW(uwhh);
            asm volatile("s_waitcnt vmcnt(0)" ::: "memory");
            __syncthreads();
        }
        const float* xsrc = (p <= 15) ? xgT + (long)p * 524288 : ugT;
        float4 xcur = *(const float4*)(xsrc + xoff);
        const _Float16* hprev = hbufs + (long)(p - 1) * 131072;

        auto issue = [&](int ck, int buf) {
            #pragma unroll
            for (int pass = 0; pass < 4; ++pass) {
                const int row = pass * 32 + srow_w;
                const _Float16* src = hprev + (long)row * 1024 + ck * 128
                                    + ((sb ^ ((row & 7) << 4)) >> 1);
                GLOAD_LDS16(src, (char*)&As[buf][0] + pass*8192 + wave*1024);
            }
        };
        issue(0, 0);

        f32x4 acc = (f32x4){0.f, 0.f, 0.f, 0.f};
        for (int ck = 0; ck < 8; ++ck) {
            __builtin_amdgcn_s_barrier();            // prev mma done everywhere
            if (ck < 7) {
                issue(ck + 1, (ck + 1) & 1);
                asm volatile("s_waitcnt vmcnt(4)" ::: "memory");  // ck landed
            } else {
                asm volatile("s_waitcnt vmcnt(0)" ::: "memory");
            }
            __builtin_amdgcn_s_barrier();            // chunk ck visible to all
            const char* abase = (const char*)&As[ck & 1][0] + arow * 256;
            #pragma unroll
            for (int kb = 0; kb < 4; ++kb) {
                const int ab = kb * 64 + ((lane >> 4) << 4);
                const f16x8 a   = *(const f16x8*)(abase + (ab ^ aswz));
                const int  wb  = ck * 256 + ab;
                const f16x8 bhi = *(const f16x8*)(wrow + ((wb ^ wswz)));
                const f16x8 blo = *(const f16x8*)(wrow + 2048 + ((wb ^ wswz)));
                acc = __builtin_amdgcn_mfma_f32_16x16x32_f16(a, bhi, acc, 0, 0, 0);
                acc = __builtin_amdgcn_mfma_f32_16x16x32_f16(a, blo, acc, 0, 0, 0);
            }
        }
        __syncthreads();                 // all mma done -> Gl overlay safe
        #pragma unroll
        for (int r = 0; r < 4; ++r)
            Gl[(wave * 16 + (lane >> 4) * 4 + r) * 16 + (lane & 15)] = acc[r];
        __syncthreads();

        do_cell(xcur, true,
                (p == 17) ? hfin : hbufs + (long)p * 131072, p == 17);
        if (p < 17) grid_barrier(p + 1);
    }
}

// ---------------------------------------------------------------------------
// Fused multi-tensor f32 -> split-f16 convert (rows [hi(K)|lo(K)]) + bias
// sums. Up to 4 ranges (n in float4 units, sh = log2(K/4)); bias range last.
// ---------------------------------------------------------------------------
__global__ __launch_bounds__(256)
void convert_multi(const float* __restrict__ s0, _Float16* __restrict__ d0, long n0, int sh0,
                   const float* __restrict__ s1, _Float16* __restrict__ d1, long n1, int sh1,
                   const float* __restrict__ s2, _Float16* __restrict__ d2, long n2, int sh2,
                   const float* __restrict__ s3, _Float16* __restrict__ d3, long n3, int sh3,
                   const float* __restrict__ ba1, const float* __restrict__ bb1,
                   const float* __restrict__ ba2, const float* __restrict__ bb2,
                   float* __restrict__ o1, float* __restrict__ o2, long nb4)
{
    long i = (long)blockIdx.x * 256 + threadIdx.x;
    const float* s; _Float16* d; int sh;
    if (i < n0)      { s = s0; d = d0; sh = sh0; }
    else { i -= n0;
    if (i < n1)      { s = s1; d = d1; sh = sh1; }
    else { i -= n1;
    if (i < n2)      { s = s2; d = d2; sh = sh2; }
    else { i -= n2;
    if (i < n3)      { s = s3; d = d3; sh = sh3; }
    else { i -= n3;
        if (i >= nb4) return;
        const long half = nb4 >> 1;
        const bool first = (i < half);
        const long k = first ? i : (i - half);
        const float4 a = ((const float4*)(first ? ba1 : ba2))[k];
        const float4 b = ((const float4*)(first ? bb1 : bb2))[k];
        float4 r; r.x = a.x + b.x; r.y = a.y + b.y;
                  r.z = a.z + b.z; r.w = a.w + b.w;
        ((float4*)(first ? o1 : o2))[k] = r;
        return;
    }}}}
    const long row = i >> sh;
    const long k4  = i & ((1L << sh) - 1);
    const float4 v = ((const float4*)s)[i];
    const float vv[4] = {v.x, v.y, v.z, v.w};
    f16x4 hi, lo;
    #pragma unroll
    for (int j = 0; j < 4; ++j) {
        hi[j] = (_Float16)vv[j];
        lo[j] = (_Float16)(vv[j] - (float)hi[j]);
    }
    ((f16x4*)d)[(row << (sh + 1)) + k4]              = hi;
    ((f16x4*)d)[(row << (sh + 1)) + (1L << sh) + k4] = lo;
}

// ---------------------------------------------------------------------------
// hproj: x[:, 1024:2048] = concat(lh,rh) @ fch_w^T + fch_b (K=126), split out.
// ---------------------------------------------------------------------------
__global__ __launch_bounds__(256)
void hproj_kernel(const float* __restrict__ lh, const float* __restrict__ rh,
                  const float* __restrict__ fchw, const float* __restrict__ fchb,
                  _Float16* __restrict__ x)
{
    __shared__ float hs[16][126];
    const int brow = blockIdx.x * 16;
    for (int idx = threadIdx.x; idx < 16 * 126; idx += 256) {
        const int r = idx / 126, k = idx % 126;
        const int grow = brow + r;
        hs[r][k] = (k < 63) ? lh[(long)grow * 63 + k]
                            : rh[(long)grow * 63 + (k - 63)];
    }
    __syncthreads();
    for (int j = threadIdx.x; j < 1024; j += 256) {
        float acc[16];
        #pragma unroll
        for (int r = 0; r < 16; ++r) acc[r] = 0.f;
        const float* wrow = fchw + (long)j * 126;
        for (int k = 0; k < 126; ++k) {
            const float w = wrow[k];
            #pragma unroll
            for (int r = 0; r < 16; ++r) acc[r] = fmaf(w, hs[r][k], acc[r]);
        }
        const float b = fchb[j];
        #pragma unroll
        for (int r = 0; r < 16; ++r) {
            const float v = acc[r] + b;
            const _Float16 hi = (_Float16)v;
            x[(long)(brow + r) * 4096 + 1024 + j] = hi;
            x[(long)(brow + r) * 4096 + 3072 + j] = (_Float16)(v - (float)hi);
        }
    }
}

// ugate = sum of 4 K-split partials + bias, output in xg-transposed layout.
__global__ __launch_bounds__(256)
void reduce4_bias(const float* __restrict__ part, const float* __restrict__ bias,
                  float* __restrict__ out)
{
    const int t = blockIdx.x * 256 + threadIdx.x;
    const long o = (long)t * 4;
    const int b   = (int)(o >> 12);
    const int rem = (int)(o & 4095);
    const int q   = rem >> 10, jb = rem & 1023;
    float4 s = *(const float4*)(part + o);
    #pragma unroll
    for (int p = 1; p < 4; ++p) {
        const float4 v = *(const float4*)(part + (long)p*524288 + o);
        s.x += v.x; s.y += v.y; s.z += v.z; s.w += v.w;
    }
    const float4 bb = *(const float4*)(bias + rem);
    const float sv[4] = {s.x + bb.x, s.y + bb.y, s.z + bb.z, s.w + bb.w};
    #pragma unroll
    for (int e = 0; e < 4; ++e) {
        const int j = jb + e;
        out[(long)(j >> 2) * 2048 + b * 16 + (j & 3) * 4 + q] = sv[e];
    }
}

// ---------------------------------------------------------------------------
// Head: per-row argmax (first-max tie-break) + logsumexp + per-row loss.
// ---------------------------------------------------------------------------
__global__ __launch_bounds__(256)
void head_kernel(const float* __restrict__ logits, const int* __restrict__ act,
                 float* __restrict__ d_out, float* __restrict__ lossbuf)
{
    const int b = blockIdx.x;
    const int tid = threadIdx.x;
    const float* row = logits + (long)b * 1000;

    float mx = -1e30f; int mi = 1 << 30;
    for (int j = tid; j < 1000; j += 256) {
        const float v = row[j];
        if (v > mx) { mx = v; mi = j; }
    }
    __shared__ float smx[256];
    __shared__ int   smi[256];
    smx[tid] = mx; smi[tid] = mi;
    __syncthreads();
    for (int s = 128; s > 0; s >>= 1) {
        if (tid < s) {
            const float v2 = smx[tid + s]; const int i2 = smi[tid + s];
            if (v2 > smx[tid] || (v2 == smx[tid] && i2 < smi[tid])) {
                smx[tid] = v2; smi[tid] = i2;
            }
        }
        __syncthreads();
    }
    const float gmx = smx[0];
    const int   gmi = smi[0];
    __syncthreads();

    float partial = 0.f;
    for (int j = tid; j < 1000; j += 256) partial += __expf(row[j] - gmx);
    smx[tid] = partial;
    __syncthreads();
    for (int s = 128; s > 0; s >>= 1) {
        if (tid < s) smx[tid] += smx[tid + s];
        __syncthreads();
    }
    if (tid == 0) {
        d_out[128000 + b] = (float)gmi;
        lossbuf[b] = gmx + logf(smx[0]) - row[act[b]];
    }
}

__global__ __launch_bounds__(128)
void loss_reduce(const float* __restrict__ lossbuf, float* __restrict__ d_out)
{
    __shared__ float s[128];
    const int tid = threadIdx.x;
    s[tid] = lossbuf[tid];
    __syncthreads();
    for (int k = 64; k > 0; k >>= 1) {
        if (tid < k) s[tid] += s[tid + k];
        __syncthreads();
    }
    if (tid == 0) d_out[128128] = s[0] / 128.f;
}

// ---------------------------------------------------------------------------
extern "C" void kernel_launch(void* const* d_in, const int* in_sizes, int n_in,
                              void* d_out, int out_size, void* d_ws, size_t ws_size,
                              hipStream_t stream)
{
    const float* feats    = (const float*)d_in[0];
    const float* lh       = (const float*)d_in[1];
    const float* rh       = (const float*)d_in[2];
    const int*   act      = (const int*)  d_in[3];
    const float* fc1_w    = (const float*)d_in[4];
    const float* fc1_b    = (const float*)d_in[5];
    const float* fch_w    = (const float*)d_in[6];
    const float* fch_b    = (const float*)d_in[7];
    const float* roll_wih = (const float*)d_in[8];
    const float* roll_whh = (const float*)d_in[9];
    const float* roll_bih = (const float*)d_in[10];
    const float* roll_bhh = (const float*)d_in[11];
    const float* un_wih   = (const float*)d_in[12];
    const float* un_whh   = (const float*)d_in[13];
    const float* un_bih   = (const float*)d_in[14];
    const float* un_bhh   = (const float*)d_in[15];
    const float* cls_w    = (const float*)d_in[16];
    const float* cls_b    = (const float*)d_in[17];

    float* out = (float*)d_out;
    char* ws = (char*)d_ws;
    size_t o = 0;
    auto alloc = [&](size_t b) { size_t r = o; o += (b + 255) & ~(size_t)255; return r; };

    // regions (temporal aliasing documented inline)
    _Float16* x_h2     = (_Float16*)(ws + alloc(2048ul*4096*2));   // A: x split, 16MiB
    char*     regB     = ws + alloc(2048ul*4096*2);                // B: 16MiB
    char*     regC     = ws + alloc(4096ul*4096*2);                // C: 32MiB
    _Float16* whhr_h2  = (_Float16*)(ws + alloc(4096ul*2048*2));   // D: 16MiB
    char*     regE     = ws + alloc(16ul*128*4096*4);              // E: 32MiB
    float*    ugate    = (float*)   (ws + alloc(128ul*4096*4));    // F: 2MiB
    _Float16* h_h2     = (_Float16*)(ws + alloc(128ul*2048*2));    // G: 512KiB
    float*    rollb    = (float*)   (ws + alloc(4096*4));
    float*    unb      = (float*)   (ws + alloc(4096*4));
    float*    lossbuf  = (float*)   (ws + alloc(128*4));
    unsigned* barctr   = (unsigned*)(ws + alloc(2048));

    _Float16* feats_h2 = (_Float16*)regB;                 // dead after xproj
    float*    part     = (float*)regB;                    // ugate partials (8MiB)
    _Float16* clsw_h2  = (_Float16*)(regB + (8ul<<20));   // 4MiB, after part dead
    _Float16* wihr_h2  = (_Float16*)regC;                 // dead after xgates
    _Float16* unwhh_h2 = (_Float16*)regC;                 // after xgates (16MiB)
    _Float16* hbufs    = (_Float16*)(regC + (16ul<<20));  // 17x256KB, after xgates
    _Float16* fc1w_h2  = (_Float16*)regE;                 // dead after xproj
    _Float16* unwih_h2 = (_Float16*)regE;                 // after xproj, dead after ugate
    float*    xgates   = (float*)regE;                    // after ugate (transposed)

    // ---- conversions wave 1: feats, roll_wih, roll_whh, fc1_w + biases ----
    // ranges (float4): 1048576 + 2097152 + 1048576 + 524288 + 2048 = 4720640
    convert_multi<<<18440, 256, 0, stream>>>(
        feats,    feats_h2, 1048576, 9,
        roll_wih, wihr_h2,  2097152, 9,
        roll_whh, whhr_h2,  1048576, 8,
        fc1_w,    fc1w_h2,  524288,  9,
        roll_bih, roll_bhh, un_bih, un_bhh, rollb, unb, 2048);
    hipMemsetAsync(barctr, 0, 2048, stream);

    // ---- x = [xproj | hproj] ----
    gemm_mfma<64, 1, true><<<dim3(16, 16, 1), 256, 0, stream>>>(
        feats_h2, 4096, 2048, fc1w_h2, 4096, 2048, fc1_b,
        x_h2, 4096, 1024, 2048, 0);
    hproj_kernel<<<128, 256, 0, stream>>>(lh, rh, fch_w, fch_b, x_h2);

    // ---- conversions wave 2: un_wih (into E, after xproj freed fc1w) ----
    convert_multi<<<8192, 256, 0, stream>>>(
        un_wih, unwih_h2, 2097152, 9,
        nullptr, nullptr, 0, 0, nullptr, nullptr, 0, 0, nullptr, nullptr, 0, 0,
        nullptr, nullptr, nullptr, nullptr, nullptr, nullptr, 0);

    // ---- ugate = x[15] @ un_wih^T + unb (K=2048 split over 4 z-slices) ----
    gemm_mfma<64, 0, false><<<dim3(64, 1, 4), 256, 0, stream>>>(
        x_h2 + 15l*128*4096, 4096, 2048, unwih_h2, 4096, 2048, nullptr,
        part, 4096, 4096, 512, 524288);                                // -> B
    reduce4_bias<<<512, 256, 0, stream>>>(part, unb, ugate);  // transposed out

    // ---- xgates = x @ roll_wih^T + rollb (transposed layout, into E) ----
    gemm_mfma<128, 2, true><<<dim3(32, 16, 1), 256, 0, stream>>>(
        x_h2, 4096, 2048, wihr_h2, 4096, 2048, rollb, xgates, 4096, 4096, 2048, 0);

    // ---- conversions wave 3: un_whh (into C), cls_w (into B+8MiB) ----
    convert_multi<<<5096, 256, 0, stream>>>(
        un_whh, unwhh_h2, 1048576, 8,
        cls_w,  clsw_h2,  256000,  8,
        nullptr, nullptr, 0, 0, nullptr, nullptr, 0, 0,
        nullptr, nullptr, nullptr, nullptr, nullptr, nullptr, 0);

    // ---- fused recurrence: 16 roll + 2 unroll steps ----
    lstm_persistent<<<NBLK, 512, 0, stream>>>(whhr_h2, unwhh_h2,
                                              xgates, ugate, hbufs, h_h2, barctr);

    // ---- classifier + head ----
    gemm_mfma<64, 0, true><<<dim3(16, 1, 1), 256, 0, stream>>>(
        h_h2, 2048, 1024, clsw_h2, 2048, 1024, cls_b, out, 1000, 1000, 1024, 0);
    head_kernel<<<128, 256, 0, stream>>>(out, act, out, lossbuf);
    loss_reduce<<<1, 128, 0, stream>>>(lossbuf, out);
}